// Round 7
// baseline (557.350 us; speedup 1.0000x reference)
//
#include <hip/hip_runtime.h>
#include <hip/hip_bf16.h>
#include <math.h>

#define L_SEQ 2048
#define NB 4
#define DMODEL 256
#define NH 8
#define DHEAD 32
#define NROW (NB*L_SEQ)

typedef __attribute__((ext_vector_type(8))) short short8;
typedef __attribute__((ext_vector_type(4))) float f32x4;

__device__ __forceinline__ float bf2f(short v) {
    union { unsigned u; float f; } x; x.u = ((unsigned)(unsigned short)v) << 16; return x.f;
}
__device__ __forceinline__ short f2bf(float f) {
    union { float f; unsigned u; } x; x.f = f;
    unsigned r = x.u + 0x7fff + ((x.u >> 16) & 1);
    return (short)(r >> 16);
}
__device__ __forceinline__ short8 zero8() {
    short8 z;
    #pragma unroll
    for (int i = 0; i < 8; ++i) z[i] = 0;
    return z;
}

// ---------------- sinusoidal positional encoding (bf16) ----------------
__global__ void pe_kernel(short* __restrict__ peb) {
    int idx = blockIdx.x*256 + threadIdx.x;      // 2048*128 total
    int l = idx >> 7, m = idx & 127;
    double ang = (double)l * exp((double)m * (-9.210340371976184/128.0));
    unsigned s = (unsigned)(unsigned short)f2bf((float)sin(ang));
    unsigned c = (unsigned)(unsigned short)f2bf((float)cos(ang));
    *(unsigned*)(peb + l*DMODEL + 2*m) = s | (c << 16);
}

// ---------------- layernorm (one wave per row) -> bf16 ----------------
__global__ void ln_kernel(const float* __restrict__ x, const float* __restrict__ gamma,
                          const float* __restrict__ beta, short* __restrict__ xnb) {
    int lane = threadIdx.x & 63;
    int row  = blockIdx.x*4 + (threadIdx.x >> 6);
    const float4 a = *(const float4*)(x + (size_t)row*DMODEL + lane*4);
    float s  = a.x+a.y+a.z+a.w;
    float s2 = a.x*a.x+a.y*a.y+a.z*a.z+a.w*a.w;
    #pragma unroll
    for (int o = 32; o; o >>= 1) { s += __shfl_xor(s,o); s2 += __shfl_xor(s2,o); }
    float mu  = s * (1.f/DMODEL);
    float var = s2 * (1.f/DMODEL) - mu*mu;
    float rst = rsqrtf(var + 1e-3f);
    const float4 g  = *(const float4*)(gamma + lane*4);
    const float4 bt = *(const float4*)(beta  + lane*4);
    short4 o;
    o.x = f2bf((a.x-mu)*rst*g.x + bt.x);
    o.y = f2bf((a.y-mu)*rst*g.y + bt.y);
    o.z = f2bf((a.z-mu)*rst*g.z + bt.z);
    o.w = f2bf((a.w-mu)*rst*g.w + bt.w);
    *(short4*)(xnb + (size_t)row*DMODEL + lane*4) = o;
}

// ---------------- weight transpose+convert: W[k][n] f32 -> WT[n][k] bf16 (5 mats) ----------------
__global__ __launch_bounds__(256)
void wcvt_kernel(const float* __restrict__ W0, const float* __restrict__ W1,
                 const float* __restrict__ W2, const float* __restrict__ W3,
                 const float* __restrict__ W4, short* __restrict__ WT) {
    const float* W = (blockIdx.z==0)?W0:(blockIdx.z==1)?W1:(blockIdx.z==2)?W2:
                     (blockIdx.z==3)?W3:W4;
    short* O = WT + (size_t)blockIdx.z*65536;
    __shared__ float s[64][65];
    const int k0 = blockIdx.x*64, n0 = blockIdx.y*64;
    const int c = threadIdx.x & 63, r4 = threadIdx.x >> 6;
    #pragma unroll
    for (int i = 0; i < 16; ++i) {
        int r = r4 + 4*i;
        s[c][r] = W[(size_t)(k0+r)*256 + n0 + c];
    }
    __syncthreads();
    #pragma unroll
    for (int i = 0; i < 16; ++i) {
        int rn = r4 + 4*i;
        O[(size_t)(n0+rn)*256 + k0 + c] = f2bf(s[rn][c]);
    }
}

// ---------------- bf16 MFMA projections: C = A @ W (+bias) ----------------
__global__ __launch_bounds__(256, 2)
void projmm_kernel(const short* __restrict__ xnb, const short* __restrict__ peb,
                   const short* __restrict__ WT,
                   const float* __restrict__ bq, const float* __restrict__ bk,
                   const float* __restrict__ bv,
                   short* __restrict__ q, short* __restrict__ kb,
                   short* __restrict__ vbuf, short* __restrict__ pbuf) {
    const int bid = blockIdx.x;
    int z, rb;
    if (bid < 384) { z = bid >> 7; rb = bid & 127; }
    else           { z = 3;        rb = bid - 384; }
    const short* A = (z == 3) ? peb : xnb;
    const short* W = WT + (size_t)z*65536;
    const int t = threadIdx.x;
    const int w = t >> 6, l = t & 63, lc = l & 15, lg = l >> 4;
    const int m0 = rb*64 + 16*w;

    short8 afr[8];
    #pragma unroll
    for (int ks = 0; ks < 8; ++ks)
        afr[ks] = *(const short8*)(A + (size_t)(m0+lc)*256 + ks*32 + lg*8);

    const f32x4 zf = {0.f,0.f,0.f,0.f};
    f32x4 acc[16];
    #pragma unroll
    for (int ct = 0; ct < 16; ++ct) acc[ct] = zf;

    #pragma unroll
    for (int ct = 0; ct < 16; ++ct) {
        #pragma unroll
        for (int ks = 0; ks < 8; ++ks) {
            const short8 bfr = *(const short8*)(W + (size_t)(ct*16+lc)*256 + ks*32 + lg*8);
            acc[ct] = __builtin_amdgcn_mfma_f32_16x16x32_bf16(afr[ks], bfr, acc[ct], 0, 0, 0);
        }
    }

    #pragma unroll
    for (int ct = 0; ct < 16; ++ct) {
        const int cc = ct*16 + lc;
        float bias = 0.f;
        if (z == 0) bias = bq[cc];
        else if (z == 1) bias = bk[cc];
        else if (z == 2) bias = bv[cc];
        #pragma unroll
        for (int r = 0; r < 4; ++r) {
            const size_t idx = (size_t)(m0 + 4*lg + r)*DMODEL + cc;
            const short v = f2bf(acc[ct][r] + bias);
            if (z == 0)      q[idx]    = v;
            else if (z == 1) kb[idx]   = v;
            else if (z == 2) vbuf[idx] = v;
            else             pbuf[idx] = v;
        }
    }
}

// ---------------- bf16 MFMA out-projection: out = ctxb @ Wo + bo (f32 out) ----------------
__global__ __launch_bounds__(256, 2)
void outmm_kernel(const short* __restrict__ ctxb, const short* __restrict__ WTo,
                  const float* __restrict__ bo, float* __restrict__ out) {
    const int rb = blockIdx.x;
    const int t = threadIdx.x;
    const int w = t >> 6, l = t & 63, lc = l & 15, lg = l >> 4;
    const int m0 = rb*64 + 16*w;

    short8 afr[8];
    #pragma unroll
    for (int ks = 0; ks < 8; ++ks)
        afr[ks] = *(const short8*)(ctxb + (size_t)(m0+lc)*256 + ks*32 + lg*8);

    const f32x4 zf = {0.f,0.f,0.f,0.f};
    f32x4 acc[16];
    #pragma unroll
    for (int ct = 0; ct < 16; ++ct) acc[ct] = zf;

    #pragma unroll
    for (int ct = 0; ct < 16; ++ct) {
        #pragma unroll
        for (int ks = 0; ks < 8; ++ks) {
            const short8 bfr = *(const short8*)(WTo + (size_t)(ct*16+lc)*256 + ks*32 + lg*8);
            acc[ct] = __builtin_amdgcn_mfma_f32_16x16x32_bf16(afr[ks], bfr, acc[ct], 0, 0, 0);
        }
    }

    #pragma unroll
    for (int ct = 0; ct < 16; ++ct) {
        const int cc = ct*16 + lc;
        const float bias = bo[cc];
        #pragma unroll
        for (int r = 0; r < 4; ++r)
            out[(size_t)(m0 + 4*lg + r)*DMODEL + cc] = acc[ct][r] + bias;
    }
}

// ---------------- V transpose: v[b,l,h,d] -> vT[b,h,d,l] ----------------
__global__ __launch_bounds__(256)
void vtrans_kernel(const short* __restrict__ v, short* __restrict__ vT) {
    const int l0 = blockIdx.x * 64;
    const int h  = blockIdx.y;
    const int b  = blockIdx.z;
    const int t  = threadIdx.x;
    __shared__ short s[32][72];
    const int r = t & 63, c8 = (t >> 6) * 8;
    short8 val = *(const short8*)(v + ((size_t)(b*L_SEQ + l0 + r))*DMODEL + h*DHEAD + c8);
    #pragma unroll
    for (int j = 0; j < 8; ++j) s[c8+j][r] = val[j];
    __syncthreads();
    const int d = t >> 3, l8 = (t & 7) * 8;
    *(short8*)(vT + (((size_t)((b*NH + h)*DHEAD + d))*L_SEQ) + l0 + l8) = *(const short8*)&s[d][l8];
}

// ---------------- fused MFMA attention: 1-WAVE blocks, barrier-free ----------------
// One wave = one (b, h, 16-q-rows). All LDS wave-private (sT[17][84] + sPk[16][32] =
// 7.8 KB -> 20 blocks/CU capacity, grid 4096 = 16/CU fully resident, NO tail round).
// Block-id swizzle: xcd = bid&7 owns head h = xcd (all batches) -> per-XCD L2 working
// set = K+V+p of one head (~1.1 MB) so the per-block K/V re-reads stay L2-resident.
// jj = (k-k0)-(q-q0)+15 in [0,78]; rho = jj + (k0-q0-17); up = (col >= 17-diff).
__global__ __launch_bounds__(64, 5)
void attn_mfma_kernel(const short* __restrict__ qg, const short* __restrict__ kb,
                      const short* __restrict__ pb, const short* __restrict__ vT,
                      const float* __restrict__ ub, const float* __restrict__ vb,
                      short* __restrict__ ctxb) {
    // swizzled decode: all 512 blocks of head h land on XCD h
    const int i0  = blockIdx.x;
    const int xcd = i0 & 7, idx = i0 >> 3;
    const int cj  = idx >> 7, qb = idx & 127;
    const int h   = xcd;
    const int b   = cj;
    const int q0  = qb * 16;
    const int l   = threadIdx.x;
    const int lc  = l & 15;
    const int lg  = l >> 4;

    __shared__ float    sT[17][84];   // rows 0..15 = T[q0+lc], row 16 = boundary (q0+16)
    __shared__ unsigned sPk[16][32];  // P bf16-pairs, XOR-swizzled; reused as ctx tile

    // fragment setup: one q load per row + in-register bias adds
    const size_t qrow = ((size_t)(b*L_SEQ + q0 + lc))*DMODEL + h*DHEAD + lg*8;
    const short8 qraw = *(const short8*)(qg + qrow);
    short8 qraw_sh = zero8();
    {
        const int r2 = q0 + lc + 1;
        if (r2 < L_SEQ)
            qraw_sh = *(const short8*)(qg + ((size_t)(b*L_SEQ + r2))*DMODEL + h*DHEAD + lg*8);
    }
    short8 aqu, aqv, aqv_sh;
    #pragma unroll
    for (int j = 0; j < 8; ++j) {
        const float u_ = ub[h*DHEAD + lg*8 + j];
        const float v_ = vb[h*DHEAD + lg*8 + j];
        const float f  = bf2f(qraw[j]);
        aqu[j]    = f2bf(f + u_);
        aqv[j]    = f2bf(f + v_);
        aqv_sh[j] = f2bf(bf2f(qraw_sh[j]) + v_);
    }

    float m_r = -3.0e38f, l_r = 0.f;
    f32x4 acc0 = {0.f,0.f,0.f,0.f}, acc1 = {0.f,0.f,0.f,0.f};

    const short* kbase = kb + ((size_t)(b*L_SEQ))*DMODEL + h*DHEAD;
    const short* pbase = pb + h*DHEAD;
    const short* vbase = vT + ((size_t)((b*NH + h)*DHEAD))*L_SEQ;
    const f32x4 zf = {0.f, 0.f, 0.f, 0.f};
    const float KSC = 0.0625f * 1.44269504088896340736f;  // (1/16)*log2(e)

    // ptilde loader for window slot cc at tile k0n: A-row jj = 16*cc + lc
    auto loadP = [&](int k0n, int cc) -> short8 {
        const int rho = (k0n - q0 - 17) + 16*cc + lc;
        if (rho == -1) return zero8();
        const int pr = rho + (rho < 0 ? (L_SEQ+1) : 0);
        return *(const short8*)(pbase + (size_t)pr*DMODEL + lg*8);
    };

    // persistent A-fragments
    short8 kfrag[4], pfrag[5];
    #pragma unroll
    for (int ct = 0; ct < 4; ++ct)
        kfrag[ct] = *(const short8*)(kbase + (size_t)(ct*16 + lc)*DMODEL + lg*8);
    #pragma unroll
    for (int cc = 0; cc < 5; ++cc) pfrag[cc] = loadP(0, cc);

    const int colc = 4*lg + 15 - lc;     // gather col = 16*ct + colc + r
    const int swkey = lc & 7;

    for (int k0 = 0; k0 < L_SEQ; k0 += 64) {
        const int diff = k0 - q0;

        // ---- content: S^T tiles (A = K, B = Qu) ----
        f32x4 cts[4];
        #pragma unroll
        for (int ct = 0; ct < 4; ++ct)
            cts[ct] = __builtin_amdgcn_mfma_f32_16x16x32_bf16(kfrag[ct], aqu, zf, 0, 0, 0);

        // ---- pos band: unshifted (rows lc) + shifted (boundary row 16, lc==15 lanes) ----
        #pragma unroll
        for (int cc = 0; cc < 5; ++cc) {
            f32x4 tt = __builtin_amdgcn_mfma_f32_16x16x32_bf16(pfrag[cc], aqv, zf, 0, 0, 0);
            *(f32x4*)&sT[lc][16*cc + 4*lg] = tt;
            f32x4 tt2 = __builtin_amdgcn_mfma_f32_16x16x32_bf16(pfrag[cc], aqv_sh, zf, 0, 0, 0);
            if (lc == 15) *(f32x4*)&sT[16][16*cc + 4*lg] = tt2;
        }

        // ---- rotate p-window (slide 64 = 4 slots) + prefetch next tile ----
        pfrag[0] = pfrag[4];
        if (k0 + 64 < L_SEQ) {
            #pragma unroll
            for (int ct = 0; ct < 4; ++ct)
                kfrag[ct] = *(const short8*)(kbase + (size_t)(k0 + 64 + ct*16 + lc)*DMODEL + lg*8);
            #pragma unroll
            for (int cc = 1; cc < 5; ++cc) pfrag[cc] = loadP(k0 + 64, cc);
        }
        // V fragments for the CURRENT tile (consumed after softmax)
        short8 vfrag[2][2];
        #pragma unroll
        for (int dt = 0; dt < 2; ++dt)
            #pragma unroll
            for (int kc = 0; kc < 2; ++kc)
                vfrag[dt][kc] = *(const short8*)(vbase + (size_t)(16*dt + lc)*L_SEQ + k0 + kc*32 + lg*8);

        asm volatile("s_waitcnt lgkmcnt(0)" ::: "memory");  // sT writes visible (intra-wave)

        // ---- rel-shift gather + combine (raw domain; scale folded into exp2 fma) ----
        float sc[4][4];
        const int cthr = 17 - diff;   // up = (col >= cthr), col in [0,78]
        if (cthr > 78) {
            const float* rowp = &sT[lc][0];
            #pragma unroll
            for (int ct = 0; ct < 4; ++ct)
                #pragma unroll
                for (int r = 0; r < 4; ++r)
                    sc[ct][r] = cts[ct][r] + rowp[16*ct + colc + r];
        } else if (cthr <= 0) {
            const float* rowp = &sT[lc+1][0];
            #pragma unroll
            for (int ct = 0; ct < 4; ++ct)
                #pragma unroll
                for (int r = 0; r < 4; ++r)
                    sc[ct][r] = cts[ct][r] + rowp[16*ct + colc + r];
        } else {
            #pragma unroll
            for (int ct = 0; ct < 4; ++ct)
                #pragma unroll
                for (int r = 0; r < 4; ++r) {
                    const int col = 16*ct + colc + r;
                    const int up = (col >= cthr) ? 1 : 0;
                    sc[ct][r] = cts[ct][r] + sT[lc + up][col];
                }
        }

        // ---- softmax: lane owns row q0+lc; in-reg reduce + 2 shfls ----
        float mx = sc[0][0];
        #pragma unroll
        for (int ct = 0; ct < 4; ++ct)
            #pragma unroll
            for (int r = 0; r < 4; ++r) mx = fmaxf(mx, sc[ct][r]);
        mx = fmaxf(mx, __shfl_xor(mx, 16));
        mx = fmaxf(mx, __shfl_xor(mx, 32));
        const float mn  = fmaxf(m_r, mx);
        const float mnK = mn * KSC;
        float ts = 0.f;
        #pragma unroll
        for (int ct = 0; ct < 4; ++ct)
            #pragma unroll
            for (int r = 0; r < 4; ++r) {
                sc[ct][r] = exp2f(fmaf(sc[ct][r], KSC, -mnK));
                ts += sc[ct][r];
            }
        ts += __shfl_xor(ts, 16);
        ts += __shfl_xor(ts, 32);
        const float alpha = exp2f(fmaf(m_r, KSC, -mnK));
        m_r = mn;
        l_r = l_r*alpha + ts;

        // ---- pack P -> sPk (bf16 pairs, XOR-block swizzle) ----
        #pragma unroll
        for (int ct = 0; ct < 4; ++ct) {
            unsigned lo, hi;
            asm("v_cvt_pk_bf16_f32 %0, %1, %2" : "=v"(lo) : "v"(sc[ct][0]), "v"(sc[ct][1]));
            asm("v_cvt_pk_bf16_f32 %0, %1, %2" : "=v"(hi) : "v"(sc[ct][2]), "v"(sc[ct][3]));
            const int kbi = 2*ct + (lg >> 1);
            const int idx = ((kbi ^ swkey) << 2) + 2*(lg & 1);
            *(uint2*)&sPk[lc][idx] = make_uint2(lo, hi);
        }
        #pragma unroll
        for (int r = 0; r < 4; ++r) { acc0[r] *= alpha; acc1[r] *= alpha; }

        asm volatile("s_waitcnt lgkmcnt(0)" ::: "memory");  // sPk writes visible (intra-wave)

        // ---- PV: ctx^T += V^T . P ----
        #pragma unroll
        for (int kc = 0; kc < 2; ++kc) {
            const int idx = ((4*kc + lg) ^ swkey) << 2;
            const short8 bp = *(const short8*)&sPk[lc][idx];
            acc0 = __builtin_amdgcn_mfma_f32_16x16x32_bf16(vfrag[0][kc], bp, acc0, 0, 0, 0);
            acc1 = __builtin_amdgcn_mfma_f32_16x16x32_bf16(vfrag[1][kc], bp, acc1, 0, 0, 0);
        }
    }

    // ---- epilogue: transpose ctx^T -> ctx through sPk space, emit bf16 ----
    asm volatile("s_waitcnt lgkmcnt(0)" ::: "memory");
    float* sCt = (float*)&sPk[0][0];   // [16][32] f32 view
    const float inv = 1.f / l_r;
    {
        f32x4 o0, o1;
        #pragma unroll
        for (int r = 0; r < 4; ++r) { o0[r] = acc0[r]*inv; o1[r] = acc1[r]*inv; }
        *(f32x4*)&sCt[lc*32 + 4*lg]      = o0;
        *(f32x4*)&sCt[lc*32 + 16 + 4*lg] = o1;
    }
    asm volatile("s_waitcnt lgkmcnt(0)" ::: "memory");
    const int rr = l >> 2;
    const int c0 = (l & 3) * 8;
    short8 ob;
    #pragma unroll
    for (int j = 0; j < 8; ++j) ob[j] = f2bf(sCt[rr*32 + c0 + j]);
    *(short8*)(ctxb + ((size_t)(b*L_SEQ + q0 + rr))*DMODEL + h*DHEAD + c0) = ob;
}

extern "C" void kernel_launch(void* const* d_in, const int* in_sizes, int n_in,
                              void* d_out, int out_size, void* d_ws, size_t ws_size,
                              hipStream_t stream) {
    (void)in_sizes; (void)n_in; (void)out_size; (void)ws_size;
    const float* x     = (const float*)d_in[0];
    const float* gamma = (const float*)d_in[1];
    const float* beta  = (const float*)d_in[2];
    const float* Wq    = (const float*)d_in[3];
    const float* bq    = (const float*)d_in[4];
    const float* Wk    = (const float*)d_in[5];
    const float* bk    = (const float*)d_in[6];
    const float* Wv    = (const float*)d_in[7];
    const float* bv    = (const float*)d_in[8];
    const float* Wp    = (const float*)d_in[9];
    const float* ub    = (const float*)d_in[10];
    const float* vb    = (const float*)d_in[11];
    const float* Wo    = (const float*)d_in[12];
    const float* bo    = (const float*)d_in[13];
    float* out = (float*)d_out;

    char* wsb = (char*)d_ws;
    short* ctxb = (short*)wsb;                                   // 4 MB bf16
    short* xnb  = (short*)(wsb + 4194304);                       // 4 MB bf16
    short* peb  = (short*)(wsb + 4194304 + 4194304);             // 1 MB bf16
    short* WT   = (short*)(wsb + 4194304 + 4194304 + 1048576);   // 640 KB bf16 (5 mats)
    short* q    = WT  + (size_t)5*65536;                         // 4 MB
    short* kbf  = q   + (size_t)NROW*DMODEL;                     // 4 MB
    short* vbf  = kbf + (size_t)NROW*DMODEL;                     // 4 MB
    short* vT   = vbf + (size_t)NROW*DMODEL;                     // 4 MB
    short* pbf  = vT  + (size_t)NROW*DMODEL;                     // 1 MB

    pe_kernel<<<1024, 256, 0, stream>>>(peb);
    ln_kernel<<<2048, 256, 0, stream>>>(x, gamma, beta, xnb);
    wcvt_kernel<<<dim3(4,4,5), 256, 0, stream>>>(Wq, Wk, Wv, Wp, Wo, WT);
    projmm_kernel<<<416, 256, 0, stream>>>(xnb, peb, WT, bq, bk, bv, q, kbf, vbf, pbf);
    vtrans_kernel<<<dim3(32,8,4), 256, 0, stream>>>(vbf, vT);
    attn_mfma_kernel<<<4096, 64, 0, stream>>>(q, kbf, pbf, vT, ub, vb, ctxb);
    outmm_kernel<<<128, 256, 0, stream>>>(ctxb, WT + (size_t)4*65536, bo, out);
}

// Round 8
// 315.404 us; speedup vs baseline: 1.7671x; 1.7671x over previous
//
#include <hip/hip_runtime.h>
#include <hip/hip_bf16.h>
#include <math.h>

#define L_SEQ 2048
#define NB 4
#define DMODEL 256
#define NH 8
#define DHEAD 32
#define NROW (NB*L_SEQ)

typedef __attribute__((ext_vector_type(8))) short short8;
typedef __attribute__((ext_vector_type(4))) float f32x4;

__device__ __forceinline__ float bf2f(short v) {
    union { unsigned u; float f; } x; x.u = ((unsigned)(unsigned short)v) << 16; return x.f;
}
__device__ __forceinline__ short f2bf(float f) {
    union { float f; unsigned u; } x; x.f = f;
    unsigned r = x.u + 0x7fff + ((x.u >> 16) & 1);
    return (short)(r >> 16);
}
__device__ __forceinline__ short8 zero8() {
    short8 z;
    #pragma unroll
    for (int i = 0; i < 8; ++i) z[i] = 0;
    return z;
}

// ---------------- sinusoidal positional encoding (bf16) ----------------
__global__ void pe_kernel(short* __restrict__ peb) {
    int idx = blockIdx.x*256 + threadIdx.x;      // 2048*128 total
    int l = idx >> 7, m = idx & 127;
    double ang = (double)l * exp((double)m * (-9.210340371976184/128.0));
    unsigned s = (unsigned)(unsigned short)f2bf((float)sin(ang));
    unsigned c = (unsigned)(unsigned short)f2bf((float)cos(ang));
    *(unsigned*)(peb + l*DMODEL + 2*m) = s | (c << 16);
}

// ---------------- layernorm (one wave per row) -> bf16 ----------------
__global__ void ln_kernel(const float* __restrict__ x, const float* __restrict__ gamma,
                          const float* __restrict__ beta, short* __restrict__ xnb) {
    int lane = threadIdx.x & 63;
    int row  = blockIdx.x*4 + (threadIdx.x >> 6);
    const float4 a = *(const float4*)(x + (size_t)row*DMODEL + lane*4);
    float s  = a.x+a.y+a.z+a.w;
    float s2 = a.x*a.x+a.y*a.y+a.z*a.z+a.w*a.w;
    #pragma unroll
    for (int o = 32; o; o >>= 1) { s += __shfl_xor(s,o); s2 += __shfl_xor(s2,o); }
    float mu  = s * (1.f/DMODEL);
    float var = s2 * (1.f/DMODEL) - mu*mu;
    float rst = rsqrtf(var + 1e-3f);
    const float4 g  = *(const float4*)(gamma + lane*4);
    const float4 bt = *(const float4*)(beta  + lane*4);
    short4 o;
    o.x = f2bf((a.x-mu)*rst*g.x + bt.x);
    o.y = f2bf((a.y-mu)*rst*g.y + bt.y);
    o.z = f2bf((a.z-mu)*rst*g.z + bt.z);
    o.w = f2bf((a.w-mu)*rst*g.w + bt.w);
    *(short4*)(xnb + (size_t)row*DMODEL + lane*4) = o;
}

// ---------------- weight transpose+convert: W[k][n] f32 -> WT[n][k] bf16 (5 mats) ----------------
__global__ __launch_bounds__(256)
void wcvt_kernel(const float* __restrict__ W0, const float* __restrict__ W1,
                 const float* __restrict__ W2, const float* __restrict__ W3,
                 const float* __restrict__ W4, short* __restrict__ WT) {
    const float* W = (blockIdx.z==0)?W0:(blockIdx.z==1)?W1:(blockIdx.z==2)?W2:
                     (blockIdx.z==3)?W3:W4;
    short* O = WT + (size_t)blockIdx.z*65536;
    __shared__ float s[64][65];
    const int k0 = blockIdx.x*64, n0 = blockIdx.y*64;
    const int c = threadIdx.x & 63, r4 = threadIdx.x >> 6;
    #pragma unroll
    for (int i = 0; i < 16; ++i) {
        int r = r4 + 4*i;
        s[c][r] = W[(size_t)(k0+r)*256 + n0 + c];
    }
    __syncthreads();
    #pragma unroll
    for (int i = 0; i < 16; ++i) {
        int rn = r4 + 4*i;
        O[(size_t)(n0+rn)*256 + k0 + c] = f2bf(s[rn][c]);
    }
}

// ---------------- bf16 MFMA projections: C = A @ W (+bias) ----------------
__global__ __launch_bounds__(256, 2)
void projmm_kernel(const short* __restrict__ xnb, const short* __restrict__ peb,
                   const short* __restrict__ WT,
                   const float* __restrict__ bq, const float* __restrict__ bk,
                   const float* __restrict__ bv,
                   short* __restrict__ q, short* __restrict__ kb,
                   short* __restrict__ vbuf, short* __restrict__ pbuf) {
    const int bid = blockIdx.x;
    int z, rb;
    if (bid < 384) { z = bid >> 7; rb = bid & 127; }
    else           { z = 3;        rb = bid - 384; }
    const short* A = (z == 3) ? peb : xnb;
    const short* W = WT + (size_t)z*65536;
    const int t = threadIdx.x;
    const int w = t >> 6, l = t & 63, lc = l & 15, lg = l >> 4;
    const int m0 = rb*64 + 16*w;

    short8 afr[8];
    #pragma unroll
    for (int ks = 0; ks < 8; ++ks)
        afr[ks] = *(const short8*)(A + (size_t)(m0+lc)*256 + ks*32 + lg*8);

    const f32x4 zf = {0.f,0.f,0.f,0.f};
    f32x4 acc[16];
    #pragma unroll
    for (int ct = 0; ct < 16; ++ct) acc[ct] = zf;

    #pragma unroll
    for (int ct = 0; ct < 16; ++ct) {
        #pragma unroll
        for (int ks = 0; ks < 8; ++ks) {
            const short8 bfr = *(const short8*)(W + (size_t)(ct*16+lc)*256 + ks*32 + lg*8);
            acc[ct] = __builtin_amdgcn_mfma_f32_16x16x32_bf16(afr[ks], bfr, acc[ct], 0, 0, 0);
        }
    }

    #pragma unroll
    for (int ct = 0; ct < 16; ++ct) {
        const int cc = ct*16 + lc;
        float bias = 0.f;
        if (z == 0) bias = bq[cc];
        else if (z == 1) bias = bk[cc];
        else if (z == 2) bias = bv[cc];
        #pragma unroll
        for (int r = 0; r < 4; ++r) {
            const size_t idx = (size_t)(m0 + 4*lg + r)*DMODEL + cc;
            const short v = f2bf(acc[ct][r] + bias);
            if (z == 0)      q[idx]    = v;
            else if (z == 1) kb[idx]   = v;
            else if (z == 2) vbuf[idx] = v;
            else             pbuf[idx] = v;
        }
    }
}

// ---------------- bf16 MFMA out-projection: out = ctxb @ Wo + bo (f32 out) ----------------
__global__ __launch_bounds__(256, 2)
void outmm_kernel(const short* __restrict__ ctxb, const short* __restrict__ WTo,
                  const float* __restrict__ bo, float* __restrict__ out) {
    const int rb = blockIdx.x;
    const int t = threadIdx.x;
    const int w = t >> 6, l = t & 63, lc = l & 15, lg = l >> 4;
    const int m0 = rb*64 + 16*w;

    short8 afr[8];
    #pragma unroll
    for (int ks = 0; ks < 8; ++ks)
        afr[ks] = *(const short8*)(ctxb + (size_t)(m0+lc)*256 + ks*32 + lg*8);

    const f32x4 zf = {0.f,0.f,0.f,0.f};
    f32x4 acc[16];
    #pragma unroll
    for (int ct = 0; ct < 16; ++ct) acc[ct] = zf;

    #pragma unroll
    for (int ct = 0; ct < 16; ++ct) {
        #pragma unroll
        for (int ks = 0; ks < 8; ++ks) {
            const short8 bfr = *(const short8*)(WTo + (size_t)(ct*16+lc)*256 + ks*32 + lg*8);
            acc[ct] = __builtin_amdgcn_mfma_f32_16x16x32_bf16(afr[ks], bfr, acc[ct], 0, 0, 0);
        }
    }

    #pragma unroll
    for (int ct = 0; ct < 16; ++ct) {
        const int cc = ct*16 + lc;
        const float bias = bo[cc];
        #pragma unroll
        for (int r = 0; r < 4; ++r)
            out[(size_t)(m0 + 4*lg + r)*DMODEL + cc] = acc[ct][r] + bias;
    }
}

// ---------------- V transpose: v[b,l,h,d] -> vT[b,h,d,l] ----------------
__global__ __launch_bounds__(256)
void vtrans_kernel(const short* __restrict__ v, short* __restrict__ vT) {
    const int l0 = blockIdx.x * 64;
    const int h  = blockIdx.y;
    const int b  = blockIdx.z;
    const int t  = threadIdx.x;
    __shared__ short s[32][72];
    const int r = t & 63, c8 = (t >> 6) * 8;
    short8 val = *(const short8*)(v + ((size_t)(b*L_SEQ + l0 + r))*DMODEL + h*DHEAD + c8);
    #pragma unroll
    for (int j = 0; j < 8; ++j) s[c8+j][r] = val[j];
    __syncthreads();
    const int d = t >> 3, l8 = (t & 7) * 8;
    *(short8*)(vT + (((size_t)((b*NH + h)*DHEAD + d))*L_SEQ) + l0 + l8) = *(const short8*)&s[d][l8];
}

// ---------------- fused MFMA attention: 1-WAVE blocks, barrier-free ----------------
// One wave = one (b, h, 16-q-rows). All LDS wave-private (7.8 KB). Grid 4096 = 16/CU,
// one full round, no tail. __launch_bounds__(64,4): VGPR cap 128 >= ~90 live state ->
// NO SPILL (round 7's (64,5) capped at 48 VGPR -> 1.8 GB scratch traffic, 2.6x slower).
// Block-id swizzle: xcd = bid&7 owns head h -> per-XCD L2 working set ~1.1 MB.
__global__ __launch_bounds__(64, 4)
void attn_mfma_kernel(const short* __restrict__ qg, const short* __restrict__ kb,
                      const short* __restrict__ pb, const short* __restrict__ vT,
                      const float* __restrict__ ub, const float* __restrict__ vb,
                      short* __restrict__ ctxb) {
    // swizzled decode: all 512 blocks of head h land on XCD h
    const int i0  = blockIdx.x;
    const int xcd = i0 & 7, idx = i0 >> 3;
    const int cj  = idx >> 7, qb = idx & 127;
    const int h   = xcd;
    const int b   = cj;
    const int q0  = qb * 16;
    const int l   = threadIdx.x;
    const int lc  = l & 15;
    const int lg  = l >> 4;

    __shared__ float    sT[17][84];   // rows 0..15 = T[q0+lc], row 16 = boundary (q0+16)
    __shared__ unsigned sPk[16][32];  // P bf16-pairs, XOR-swizzled; reused as ctx tile

    // fragment setup: one q load per row + in-register bias adds
    const size_t qrow = ((size_t)(b*L_SEQ + q0 + lc))*DMODEL + h*DHEAD + lg*8;
    const short8 qraw = *(const short8*)(qg + qrow);
    short8 qraw_sh = zero8();
    {
        const int r2 = q0 + lc + 1;
        if (r2 < L_SEQ)
            qraw_sh = *(const short8*)(qg + ((size_t)(b*L_SEQ + r2))*DMODEL + h*DHEAD + lg*8);
    }
    short8 aqu, aqv, aqv_sh;
    #pragma unroll
    for (int j = 0; j < 8; ++j) {
        const float u_ = ub[h*DHEAD + lg*8 + j];
        const float v_ = vb[h*DHEAD + lg*8 + j];
        const float f  = bf2f(qraw[j]);
        aqu[j]    = f2bf(f + u_);
        aqv[j]    = f2bf(f + v_);
        aqv_sh[j] = f2bf(bf2f(qraw_sh[j]) + v_);
    }

    float m_r = -3.0e38f, l_r = 0.f;
    f32x4 acc0 = {0.f,0.f,0.f,0.f}, acc1 = {0.f,0.f,0.f,0.f};

    const short* kbase = kb + ((size_t)(b*L_SEQ))*DMODEL + h*DHEAD;
    const short* pbase = pb + h*DHEAD;
    const short* vbase = vT + ((size_t)((b*NH + h)*DHEAD))*L_SEQ;
    const f32x4 zf = {0.f, 0.f, 0.f, 0.f};
    const float KSC = 0.0625f * 1.44269504088896340736f;  // (1/16)*log2(e)

    // ptilde loader for window slot cc at tile k0n: A-row jj = 16*cc + lc
    auto loadP = [&](int k0n, int cc) -> short8 {
        const int rho = (k0n - q0 - 17) + 16*cc + lc;
        if (rho == -1) return zero8();
        const int pr = rho + (rho < 0 ? (L_SEQ+1) : 0);
        return *(const short8*)(pbase + (size_t)pr*DMODEL + lg*8);
    };

    // persistent A-fragments
    short8 kfrag[4], pfrag[5];
    #pragma unroll
    for (int ct = 0; ct < 4; ++ct)
        kfrag[ct] = *(const short8*)(kbase + (size_t)(ct*16 + lc)*DMODEL + lg*8);
    #pragma unroll
    for (int cc = 0; cc < 5; ++cc) pfrag[cc] = loadP(0, cc);

    const int colc = 4*lg + 15 - lc;     // gather col = 16*ct + colc + r
    const int swkey = lc & 7;

    for (int k0 = 0; k0 < L_SEQ; k0 += 64) {
        const int diff = k0 - q0;

        // ---- content: S^T tiles (A = K, B = Qu) ----
        f32x4 cts[4];
        #pragma unroll
        for (int ct = 0; ct < 4; ++ct)
            cts[ct] = __builtin_amdgcn_mfma_f32_16x16x32_bf16(kfrag[ct], aqu, zf, 0, 0, 0);

        // ---- pos band: unshifted (rows lc) + shifted (boundary row 16, lc==15 lanes) ----
        #pragma unroll
        for (int cc = 0; cc < 5; ++cc) {
            f32x4 tt = __builtin_amdgcn_mfma_f32_16x16x32_bf16(pfrag[cc], aqv, zf, 0, 0, 0);
            *(f32x4*)&sT[lc][16*cc + 4*lg] = tt;
            f32x4 tt2 = __builtin_amdgcn_mfma_f32_16x16x32_bf16(pfrag[cc], aqv_sh, zf, 0, 0, 0);
            if (lc == 15) *(f32x4*)&sT[16][16*cc + 4*lg] = tt2;
        }

        // ---- rotate p-window (slide 64 = 4 slots) + prefetch next tile ----
        pfrag[0] = pfrag[4];
        if (k0 + 64 < L_SEQ) {
            #pragma unroll
            for (int ct = 0; ct < 4; ++ct)
                kfrag[ct] = *(const short8*)(kbase + (size_t)(k0 + 64 + ct*16 + lc)*DMODEL + lg*8);
            #pragma unroll
            for (int cc = 1; cc < 5; ++cc) pfrag[cc] = loadP(k0 + 64, cc);
        }
        // V fragments for the CURRENT tile (consumed after softmax)
        short8 vfrag[2][2];
        #pragma unroll
        for (int dt = 0; dt < 2; ++dt)
            #pragma unroll
            for (int kc = 0; kc < 2; ++kc)
                vfrag[dt][kc] = *(const short8*)(vbase + (size_t)(16*dt + lc)*L_SEQ + k0 + kc*32 + lg*8);

        asm volatile("s_waitcnt lgkmcnt(0)" ::: "memory");  // sT writes visible (intra-wave)

        // ---- rel-shift gather + combine (raw domain; scale folded into exp2 fma) ----
        float sc[4][4];
        const int cthr = 17 - diff;   // up = (col >= cthr), col in [0,78]
        if (cthr > 78) {
            const float* rowp = &sT[lc][0];
            #pragma unroll
            for (int ct = 0; ct < 4; ++ct)
                #pragma unroll
                for (int r = 0; r < 4; ++r)
                    sc[ct][r] = cts[ct][r] + rowp[16*ct + colc + r];
        } else if (cthr <= 0) {
            const float* rowp = &sT[lc+1][0];
            #pragma unroll
            for (int ct = 0; ct < 4; ++ct)
                #pragma unroll
                for (int r = 0; r < 4; ++r)
                    sc[ct][r] = cts[ct][r] + rowp[16*ct + colc + r];
        } else {
            #pragma unroll
            for (int ct = 0; ct < 4; ++ct)
                #pragma unroll
                for (int r = 0; r < 4; ++r) {
                    const int col = 16*ct + colc + r;
                    const int up = (col >= cthr) ? 1 : 0;
                    sc[ct][r] = cts[ct][r] + sT[lc + up][col];
                }
        }

        // ---- softmax: lane owns row q0+lc; in-reg reduce + 2 shfls ----
        float mx = sc[0][0];
        #pragma unroll
        for (int ct = 0; ct < 4; ++ct)
            #pragma unroll
            for (int r = 0; r < 4; ++r) mx = fmaxf(mx, sc[ct][r]);
        mx = fmaxf(mx, __shfl_xor(mx, 16));
        mx = fmaxf(mx, __shfl_xor(mx, 32));
        const float mn  = fmaxf(m_r, mx);
        const float mnK = mn * KSC;
        float ts = 0.f;
        #pragma unroll
        for (int ct = 0; ct < 4; ++ct)
            #pragma unroll
            for (int r = 0; r < 4; ++r) {
                sc[ct][r] = exp2f(fmaf(sc[ct][r], KSC, -mnK));
                ts += sc[ct][r];
            }
        ts += __shfl_xor(ts, 16);
        ts += __shfl_xor(ts, 32);
        const float alpha = exp2f(fmaf(m_r, KSC, -mnK));
        m_r = mn;
        l_r = l_r*alpha + ts;

        // ---- pack P -> sPk (bf16 pairs, XOR-block swizzle) ----
        #pragma unroll
        for (int ct = 0; ct < 4; ++ct) {
            unsigned lo, hi;
            asm("v_cvt_pk_bf16_f32 %0, %1, %2" : "=v"(lo) : "v"(sc[ct][0]), "v"(sc[ct][1]));
            asm("v_cvt_pk_bf16_f32 %0, %1, %2" : "=v"(hi) : "v"(sc[ct][2]), "v"(sc[ct][3]));
            const int kbi = 2*ct + (lg >> 1);
            const int idx = ((kbi ^ swkey) << 2) + 2*(lg & 1);
            *(uint2*)&sPk[lc][idx] = make_uint2(lo, hi);
        }
        #pragma unroll
        for (int r = 0; r < 4; ++r) { acc0[r] *= alpha; acc1[r] *= alpha; }

        asm volatile("s_waitcnt lgkmcnt(0)" ::: "memory");  // sPk writes visible (intra-wave)

        // ---- PV: ctx^T += V^T . P ----
        #pragma unroll
        for (int kc = 0; kc < 2; ++kc) {
            const int idx = ((4*kc + lg) ^ swkey) << 2;
            const short8 bp = *(const short8*)&sPk[lc][idx];
            acc0 = __builtin_amdgcn_mfma_f32_16x16x32_bf16(vfrag[0][kc], bp, acc0, 0, 0, 0);
            acc1 = __builtin_amdgcn_mfma_f32_16x16x32_bf16(vfrag[1][kc], bp, acc1, 0, 0, 0);
        }
    }

    // ---- epilogue: transpose ctx^T -> ctx through sPk space, emit bf16 ----
    asm volatile("s_waitcnt lgkmcnt(0)" ::: "memory");
    float* sCt = (float*)&sPk[0][0];   // [16][32] f32 view
    const float inv = 1.f / l_r;
    {
        f32x4 o0, o1;
        #pragma unroll
        for (int r = 0; r < 4; ++r) { o0[r] = acc0[r]*inv; o1[r] = acc1[r]*inv; }
        *(f32x4*)&sCt[lc*32 + 4*lg]      = o0;
        *(f32x4*)&sCt[lc*32 + 16 + 4*lg] = o1;
    }
    asm volatile("s_waitcnt lgkmcnt(0)" ::: "memory");
    const int rr = l >> 2;
    const int c0 = (l & 3) * 8;
    short8 ob;
    #pragma unroll
    for (int j = 0; j < 8; ++j) ob[j] = f2bf(sCt[rr*32 + c0 + j]);
    *(short8*)(ctxb + ((size_t)(b*L_SEQ + q0 + rr))*DMODEL + h*DHEAD + c0) = ob;
}

extern "C" void kernel_launch(void* const* d_in, const int* in_sizes, int n_in,
                              void* d_out, int out_size, void* d_ws, size_t ws_size,
                              hipStream_t stream) {
    (void)in_sizes; (void)n_in; (void)out_size; (void)ws_size;
    const float* x     = (const float*)d_in[0];
    const float* gamma = (const float*)d_in[1];
    const float* beta  = (const float*)d_in[2];
    const float* Wq    = (const float*)d_in[3];
    const float* bq    = (const float*)d_in[4];
    const float* Wk    = (const float*)d_in[5];
    const float* bk    = (const float*)d_in[6];
    const float* Wv    = (const float*)d_in[7];
    const float* bv    = (const float*)d_in[8];
    const float* Wp    = (const float*)d_in[9];
    const float* ub    = (const float*)d_in[10];
    const float* vb    = (const float*)d_in[11];
    const float* Wo    = (const float*)d_in[12];
    const float* bo    = (const float*)d_in[13];
    float* out = (float*)d_out;

    char* wsb = (char*)d_ws;
    short* ctxb = (short*)wsb;                                   // 4 MB bf16
    short* xnb  = (short*)(wsb + 4194304);                       // 4 MB bf16
    short* peb  = (short*)(wsb + 4194304 + 4194304);             // 1 MB bf16
    short* WT   = (short*)(wsb + 4194304 + 4194304 + 1048576);   // 640 KB bf16 (5 mats)
    short* q    = WT  + (size_t)5*65536;                         // 4 MB
    short* kbf  = q   + (size_t)NROW*DMODEL;                     // 4 MB
    short* vbf  = kbf + (size_t)NROW*DMODEL;                     // 4 MB
    short* vT   = vbf + (size_t)NROW*DMODEL;                     // 4 MB
    short* pbf  = vT  + (size_t)NROW*DMODEL;                     // 1 MB

    pe_kernel<<<1024, 256, 0, stream>>>(peb);
    ln_kernel<<<2048, 256, 0, stream>>>(x, gamma, beta, xnb);
    wcvt_kernel<<<dim3(4,4,5), 256, 0, stream>>>(Wq, Wk, Wv, Wp, Wo, WT);
    projmm_kernel<<<416, 256, 0, stream>>>(xnb, peb, WT, bq, bk, bv, q, kbf, vbf, pbf);
    vtrans_kernel<<<dim3(32,8,4), 256, 0, stream>>>(vbf, vT);
    attn_mfma_kernel<<<4096, 64, 0, stream>>>(q, kbf, pbf, vT, ub, vb, ctxb);
    outmm_kernel<<<128, 256, 0, stream>>>(ctxb, WT + (size_t)4*65536, bo, out);
}

// Round 9
// 249.614 us; speedup vs baseline: 2.2329x; 1.2636x over previous
//
#include <hip/hip_runtime.h>
#include <hip/hip_bf16.h>
#include <math.h>

#define L_SEQ 2048
#define NB 4
#define DMODEL 256
#define NH 8
#define DHEAD 32
#define NROW (NB*L_SEQ)

typedef __attribute__((ext_vector_type(8))) short short8;
typedef __attribute__((ext_vector_type(4))) float f32x4;

__device__ __forceinline__ float bf2f(short v) {
    union { unsigned u; float f; } x; x.u = ((unsigned)(unsigned short)v) << 16; return x.f;
}
__device__ __forceinline__ short f2bf(float f) {
    union { float f; unsigned u; } x; x.f = f;
    unsigned r = x.u + 0x7fff + ((x.u >> 16) & 1);
    return (short)(r >> 16);
}
__device__ __forceinline__ short8 zero8() {
    short8 z;
    #pragma unroll
    for (int i = 0; i < 8; ++i) z[i] = 0;
    return z;
}

// ---------------- sinusoidal positional encoding (bf16) ----------------
__global__ void pe_kernel(short* __restrict__ peb) {
    int idx = blockIdx.x*256 + threadIdx.x;      // 2048*128 total
    int l = idx >> 7, m = idx & 127;
    double ang = (double)l * exp((double)m * (-9.210340371976184/128.0));
    unsigned s = (unsigned)(unsigned short)f2bf((float)sin(ang));
    unsigned c = (unsigned)(unsigned short)f2bf((float)cos(ang));
    *(unsigned*)(peb + l*DMODEL + 2*m) = s | (c << 16);
}

// ---------------- layernorm (one wave per row) -> bf16 ----------------
__global__ void ln_kernel(const float* __restrict__ x, const float* __restrict__ gamma,
                          const float* __restrict__ beta, short* __restrict__ xnb) {
    int lane = threadIdx.x & 63;
    int row  = blockIdx.x*4 + (threadIdx.x >> 6);
    const float4 a = *(const float4*)(x + (size_t)row*DMODEL + lane*4);
    float s  = a.x+a.y+a.z+a.w;
    float s2 = a.x*a.x+a.y*a.y+a.z*a.z+a.w*a.w;
    #pragma unroll
    for (int o = 32; o; o >>= 1) { s += __shfl_xor(s,o); s2 += __shfl_xor(s2,o); }
    float mu  = s * (1.f/DMODEL);
    float var = s2 * (1.f/DMODEL) - mu*mu;
    float rst = rsqrtf(var + 1e-3f);
    const float4 g  = *(const float4*)(gamma + lane*4);
    const float4 bt = *(const float4*)(beta  + lane*4);
    short4 o;
    o.x = f2bf((a.x-mu)*rst*g.x + bt.x);
    o.y = f2bf((a.y-mu)*rst*g.y + bt.y);
    o.z = f2bf((a.z-mu)*rst*g.z + bt.z);
    o.w = f2bf((a.w-mu)*rst*g.w + bt.w);
    *(short4*)(xnb + (size_t)row*DMODEL + lane*4) = o;
}

// ---------------- weight transpose+convert: W[k][n] f32 -> WT[n][k] bf16 (5 mats) ----------------
__global__ __launch_bounds__(256)
void wcvt_kernel(const float* __restrict__ W0, const float* __restrict__ W1,
                 const float* __restrict__ W2, const float* __restrict__ W3,
                 const float* __restrict__ W4, short* __restrict__ WT) {
    const float* W = (blockIdx.z==0)?W0:(blockIdx.z==1)?W1:(blockIdx.z==2)?W2:
                     (blockIdx.z==3)?W3:W4;
    short* O = WT + (size_t)blockIdx.z*65536;
    __shared__ float s[64][65];
    const int k0 = blockIdx.x*64, n0 = blockIdx.y*64;
    const int c = threadIdx.x & 63, r4 = threadIdx.x >> 6;
    #pragma unroll
    for (int i = 0; i < 16; ++i) {
        int r = r4 + 4*i;
        s[c][r] = W[(size_t)(k0+r)*256 + n0 + c];
    }
    __syncthreads();
    #pragma unroll
    for (int i = 0; i < 16; ++i) {
        int rn = r4 + 4*i;
        O[(size_t)(n0+rn)*256 + k0 + c] = f2bf(s[rn][c]);
    }
}

// ---------------- bf16 MFMA projections: C = A @ W (+bias) ----------------
// z==2 (V projection) writes DIRECTLY to vT[b,h,d,l]: acc regs r=0..3 are contiguous
// in l (= m0+4lg+r), vT's contiguous axis -> short4 stores; vtrans kernel eliminated.
__global__ __launch_bounds__(256, 2)
void projmm_kernel(const short* __restrict__ xnb, const short* __restrict__ peb,
                   const short* __restrict__ WT,
                   const float* __restrict__ bq, const float* __restrict__ bk,
                   const float* __restrict__ bv,
                   short* __restrict__ q, short* __restrict__ kb,
                   short* __restrict__ vT, short* __restrict__ pbuf) {
    const int bid = blockIdx.x;
    int z, rb;
    if (bid < 384) { z = bid >> 7; rb = bid & 127; }
    else           { z = 3;        rb = bid - 384; }
    const short* A = (z == 3) ? peb : xnb;
    const short* W = WT + (size_t)z*65536;
    const int t = threadIdx.x;
    const int w = t >> 6, l = t & 63, lc = l & 15, lg = l >> 4;
    const int m0 = rb*64 + 16*w;

    short8 afr[8];
    #pragma unroll
    for (int ks = 0; ks < 8; ++ks)
        afr[ks] = *(const short8*)(A + (size_t)(m0+lc)*256 + ks*32 + lg*8);

    const f32x4 zf = {0.f,0.f,0.f,0.f};
    f32x4 acc[16];
    #pragma unroll
    for (int ct = 0; ct < 16; ++ct) acc[ct] = zf;

    #pragma unroll
    for (int ct = 0; ct < 16; ++ct) {
        #pragma unroll
        for (int ks = 0; ks < 8; ++ks) {
            const short8 bfr = *(const short8*)(W + (size_t)(ct*16+lc)*256 + ks*32 + lg*8);
            acc[ct] = __builtin_amdgcn_mfma_f32_16x16x32_bf16(afr[ks], bfr, acc[ct], 0, 0, 0);
        }
    }

    if (z == 2) {
        // V: write transposed into vT[b,h,d,l]
        const int bb = m0 >> 11;
        const int l0 = (m0 & 2047) + 4*lg;
        #pragma unroll
        for (int ct = 0; ct < 16; ++ct) {
            const int cc = ct*16 + lc;
            const float bias = bv[cc];
            const int hh = cc >> 5, dd = cc & 31;
            short4 o;
            o.x = f2bf(acc[ct][0] + bias);
            o.y = f2bf(acc[ct][1] + bias);
            o.z = f2bf(acc[ct][2] + bias);
            o.w = f2bf(acc[ct][3] + bias);
            *(short4*)(vT + ((size_t)((bb*NH + hh)*DHEAD + dd))*L_SEQ + l0) = o;
        }
    } else {
        #pragma unroll
        for (int ct = 0; ct < 16; ++ct) {
            const int cc = ct*16 + lc;
            float bias = 0.f;
            if (z == 0) bias = bq[cc];
            else if (z == 1) bias = bk[cc];
            #pragma unroll
            for (int r = 0; r < 4; ++r) {
                const size_t idx = (size_t)(m0 + 4*lg + r)*DMODEL + cc;
                const short v = f2bf(acc[ct][r] + bias);
                if (z == 0)      q[idx]    = v;
                else if (z == 1) kb[idx]   = v;
                else             pbuf[idx] = v;
            }
        }
    }
}

// ---------------- bf16 MFMA out-projection: out = ctxb @ Wo + bo (f32 out) ----------------
__global__ __launch_bounds__(256, 2)
void outmm_kernel(const short* __restrict__ ctxb, const short* __restrict__ WTo,
                  const float* __restrict__ bo, float* __restrict__ out) {
    const int rb = blockIdx.x;
    const int t = threadIdx.x;
    const int w = t >> 6, l = t & 63, lc = l & 15, lg = l >> 4;
    const int m0 = rb*64 + 16*w;

    short8 afr[8];
    #pragma unroll
    for (int ks = 0; ks < 8; ++ks)
        afr[ks] = *(const short8*)(ctxb + (size_t)(m0+lc)*256 + ks*32 + lg*8);

    const f32x4 zf = {0.f,0.f,0.f,0.f};
    f32x4 acc[16];
    #pragma unroll
    for (int ct = 0; ct < 16; ++ct) acc[ct] = zf;

    #pragma unroll
    for (int ct = 0; ct < 16; ++ct) {
        #pragma unroll
        for (int ks = 0; ks < 8; ++ks) {
            const short8 bfr = *(const short8*)(WTo + (size_t)(ct*16+lc)*256 + ks*32 + lg*8);
            acc[ct] = __builtin_amdgcn_mfma_f32_16x16x32_bf16(afr[ks], bfr, acc[ct], 0, 0, 0);
        }
    }

    #pragma unroll
    for (int ct = 0; ct < 16; ++ct) {
        const int cc = ct*16 + lc;
        const float bias = bo[cc];
        #pragma unroll
        for (int r = 0; r < 4; ++r)
            out[(size_t)(m0 + 4*lg + r)*DMODEL + cc] = acc[ct][r] + bias;
    }
}

// ---------------- fused MFMA attention: 1-WAVE blocks, barrier-free ----------------
// One wave = one (b, h, 16-q-rows). All LDS wave-private (7.8 KB -> 20 blocks/CU).
// NO min-waves launch bound: (64,5) forced VGPR=48, (64,4) forced VGPR=64 -> both
// spilled the ~100-reg fragment state (21-880 MB scratch traffic). Unconstrained,
// the allocator takes ~100 VGPR -> 5 waves/SIMD = 20/CU capacity >= the 16/CU needed
// for a single full round of the 4096-block grid.
// Block-id swizzle: xcd = bid&7 owns head h -> per-XCD L2 working set ~1.1 MB.
__global__ __launch_bounds__(64)
void attn_mfma_kernel(const short* __restrict__ qg, const short* __restrict__ kb,
                      const short* __restrict__ pb, const short* __restrict__ vT,
                      const float* __restrict__ ub, const float* __restrict__ vb,
                      short* __restrict__ ctxb) {
    // swizzled decode: all 512 blocks of head h land on XCD h
    const int i0  = blockIdx.x;
    const int xcd = i0 & 7, idx = i0 >> 3;
    const int cj  = idx >> 7, qb = idx & 127;
    const int h   = xcd;
    const int b   = cj;
    const int q0  = qb * 16;
    const int l   = threadIdx.x;
    const int lc  = l & 15;
    const int lg  = l >> 4;

    __shared__ float    sT[17][84];   // rows 0..15 = T[q0+lc], row 16 = boundary (q0+16)
    __shared__ unsigned sPk[16][32];  // P bf16-pairs, XOR-swizzled; reused as ctx tile

    // fragment setup: one q load per row + in-register bias adds
    const size_t qrow = ((size_t)(b*L_SEQ + q0 + lc))*DMODEL + h*DHEAD + lg*8;
    const short8 qraw = *(const short8*)(qg + qrow);
    short8 qraw_sh = zero8();
    {
        const int r2 = q0 + lc + 1;
        if (r2 < L_SEQ)
            qraw_sh = *(const short8*)(qg + ((size_t)(b*L_SEQ + r2))*DMODEL + h*DHEAD + lg*8);
    }
    short8 aqu, aqv, aqv_sh;
    #pragma unroll
    for (int j = 0; j < 8; ++j) {
        const float u_ = ub[h*DHEAD + lg*8 + j];
        const float v_ = vb[h*DHEAD + lg*8 + j];
        const float f  = bf2f(qraw[j]);
        aqu[j]    = f2bf(f + u_);
        aqv[j]    = f2bf(f + v_);
        aqv_sh[j] = f2bf(bf2f(qraw_sh[j]) + v_);
    }

    float m_r = -3.0e38f, l_r = 0.f;
    f32x4 acc0 = {0.f,0.f,0.f,0.f}, acc1 = {0.f,0.f,0.f,0.f};

    const short* kbase = kb + ((size_t)(b*L_SEQ))*DMODEL + h*DHEAD;
    const short* pbase = pb + h*DHEAD;
    const short* vbase = vT + ((size_t)((b*NH + h)*DHEAD))*L_SEQ;
    const f32x4 zf = {0.f, 0.f, 0.f, 0.f};
    const float KSC = 0.0625f * 1.44269504088896340736f;  // (1/16)*log2(e)

    // ptilde loader for window slot cc at tile k0n: A-row jj = 16*cc + lc
    auto loadP = [&](int k0n, int cc) -> short8 {
        const int rho = (k0n - q0 - 17) + 16*cc + lc;
        if (rho == -1) return zero8();
        const int pr = rho + (rho < 0 ? (L_SEQ+1) : 0);
        return *(const short8*)(pbase + (size_t)pr*DMODEL + lg*8);
    };

    // persistent A-fragments
    short8 kfrag[4], pfrag[5];
    #pragma unroll
    for (int ct = 0; ct < 4; ++ct)
        kfrag[ct] = *(const short8*)(kbase + (size_t)(ct*16 + lc)*DMODEL + lg*8);
    #pragma unroll
    for (int cc = 0; cc < 5; ++cc) pfrag[cc] = loadP(0, cc);

    const int colc = 4*lg + 15 - lc;     // gather col = 16*ct + colc + r
    const int swkey = lc & 7;

    for (int k0 = 0; k0 < L_SEQ; k0 += 64) {
        const int diff = k0 - q0;

        // ---- content: S^T tiles (A = K, B = Qu) ----
        f32x4 cts[4];
        #pragma unroll
        for (int ct = 0; ct < 4; ++ct)
            cts[ct] = __builtin_amdgcn_mfma_f32_16x16x32_bf16(kfrag[ct], aqu, zf, 0, 0, 0);

        // ---- pos band: unshifted (rows lc) + shifted (boundary row 16, lc==15 lanes) ----
        #pragma unroll
        for (int cc = 0; cc < 5; ++cc) {
            f32x4 tt = __builtin_amdgcn_mfma_f32_16x16x32_bf16(pfrag[cc], aqv, zf, 0, 0, 0);
            *(f32x4*)&sT[lc][16*cc + 4*lg] = tt;
            f32x4 tt2 = __builtin_amdgcn_mfma_f32_16x16x32_bf16(pfrag[cc], aqv_sh, zf, 0, 0, 0);
            if (lc == 15) *(f32x4*)&sT[16][16*cc + 4*lg] = tt2;
        }

        // ---- rotate p-window (slide 64 = 4 slots) + prefetch next tile ----
        pfrag[0] = pfrag[4];
        if (k0 + 64 < L_SEQ) {
            #pragma unroll
            for (int ct = 0; ct < 4; ++ct)
                kfrag[ct] = *(const short8*)(kbase + (size_t)(k0 + 64 + ct*16 + lc)*DMODEL + lg*8);
            #pragma unroll
            for (int cc = 1; cc < 5; ++cc) pfrag[cc] = loadP(k0 + 64, cc);
        }
        // V fragments for the CURRENT tile (consumed after softmax)
        short8 vfrag[2][2];
        #pragma unroll
        for (int dt = 0; dt < 2; ++dt)
            #pragma unroll
            for (int kc = 0; kc < 2; ++kc)
                vfrag[dt][kc] = *(const short8*)(vbase + (size_t)(16*dt + lc)*L_SEQ + k0 + kc*32 + lg*8);

        asm volatile("s_waitcnt lgkmcnt(0)" ::: "memory");  // sT writes visible (intra-wave)

        // ---- rel-shift gather + combine (raw domain; scale folded into exp2 fma) ----
        float sc[4][4];
        const int cthr = 17 - diff;   // up = (col >= cthr), col in [0,78]
        if (cthr > 78) {
            const float* rowp = &sT[lc][0];
            #pragma unroll
            for (int ct = 0; ct < 4; ++ct)
                #pragma unroll
                for (int r = 0; r < 4; ++r)
                    sc[ct][r] = cts[ct][r] + rowp[16*ct + colc + r];
        } else if (cthr <= 0) {
            const float* rowp = &sT[lc+1][0];
            #pragma unroll
            for (int ct = 0; ct < 4; ++ct)
                #pragma unroll
                for (int r = 0; r < 4; ++r)
                    sc[ct][r] = cts[ct][r] + rowp[16*ct + colc + r];
        } else {
            #pragma unroll
            for (int ct = 0; ct < 4; ++ct)
                #pragma unroll
                for (int r = 0; r < 4; ++r) {
                    const int col = 16*ct + colc + r;
                    const int up = (col >= cthr) ? 1 : 0;
                    sc[ct][r] = cts[ct][r] + sT[lc + up][col];
                }
        }

        // ---- softmax: lane owns row q0+lc; in-reg reduce + 2 shfls ----
        float mx = sc[0][0];
        #pragma unroll
        for (int ct = 0; ct < 4; ++ct)
            #pragma unroll
            for (int r = 0; r < 4; ++r) mx = fmaxf(mx, sc[ct][r]);
        mx = fmaxf(mx, __shfl_xor(mx, 16));
        mx = fmaxf(mx, __shfl_xor(mx, 32));
        const float mn  = fmaxf(m_r, mx);
        const float mnK = mn * KSC;
        float ts = 0.f;
        #pragma unroll
        for (int ct = 0; ct < 4; ++ct)
            #pragma unroll
            for (int r = 0; r < 4; ++r) {
                sc[ct][r] = exp2f(fmaf(sc[ct][r], KSC, -mnK));
                ts += sc[ct][r];
            }
        ts += __shfl_xor(ts, 16);
        ts += __shfl_xor(ts, 32);
        const float alpha = exp2f(fmaf(m_r, KSC, -mnK));
        m_r = mn;
        l_r = l_r*alpha + ts;

        // ---- pack P -> sPk (bf16 pairs, XOR-block swizzle) ----
        #pragma unroll
        for (int ct = 0; ct < 4; ++ct) {
            unsigned lo, hi;
            asm("v_cvt_pk_bf16_f32 %0, %1, %2" : "=v"(lo) : "v"(sc[ct][0]), "v"(sc[ct][1]));
            asm("v_cvt_pk_bf16_f32 %0, %1, %2" : "=v"(hi) : "v"(sc[ct][2]), "v"(sc[ct][3]));
            const int kbi = 2*ct + (lg >> 1);
            const int idx = ((kbi ^ swkey) << 2) + 2*(lg & 1);
            *(uint2*)&sPk[lc][idx] = make_uint2(lo, hi);
        }
        #pragma unroll
        for (int r = 0; r < 4; ++r) { acc0[r] *= alpha; acc1[r] *= alpha; }

        asm volatile("s_waitcnt lgkmcnt(0)" ::: "memory");  // sPk writes visible (intra-wave)

        // ---- PV: ctx^T += V^T . P ----
        #pragma unroll
        for (int kc = 0; kc < 2; ++kc) {
            const int idx = ((4*kc + lg) ^ swkey) << 2;
            const short8 bp = *(const short8*)&sPk[lc][idx];
            acc0 = __builtin_amdgcn_mfma_f32_16x16x32_bf16(vfrag[0][kc], bp, acc0, 0, 0, 0);
            acc1 = __builtin_amdgcn_mfma_f32_16x16x32_bf16(vfrag[1][kc], bp, acc1, 0, 0, 0);
        }
    }

    // ---- epilogue: transpose ctx^T -> ctx through sPk space, emit bf16 ----
    asm volatile("s_waitcnt lgkmcnt(0)" ::: "memory");
    float* sCt = (float*)&sPk[0][0];   // [16][32] f32 view
    const float inv = 1.f / l_r;
    {
        f32x4 o0, o1;
        #pragma unroll
        for (int r = 0; r < 4; ++r) { o0[r] = acc0[r]*inv; o1[r] = acc1[r]*inv; }
        *(f32x4*)&sCt[lc*32 + 4*lg]      = o0;
        *(f32x4*)&sCt[lc*32 + 16 + 4*lg] = o1;
    }
    asm volatile("s_waitcnt lgkmcnt(0)" ::: "memory");
    const int rr = l >> 2;
    const int c0 = (l & 3) * 8;
    short8 ob;
    #pragma unroll
    for (int j = 0; j < 8; ++j) ob[j] = f2bf(sCt[rr*32 + c0 + j]);
    *(short8*)(ctxb + ((size_t)(b*L_SEQ + q0 + rr))*DMODEL + h*DHEAD + c0) = ob;
}

extern "C" void kernel_launch(void* const* d_in, const int* in_sizes, int n_in,
                              void* d_out, int out_size, void* d_ws, size_t ws_size,
                              hipStream_t stream) {
    (void)in_sizes; (void)n_in; (void)out_size; (void)ws_size;
    const float* x     = (const float*)d_in[0];
    const float* gamma = (const float*)d_in[1];
    const float* beta  = (const float*)d_in[2];
    const float* Wq    = (const float*)d_in[3];
    const float* bq    = (const float*)d_in[4];
    const float* Wk    = (const float*)d_in[5];
    const float* bk    = (const float*)d_in[6];
    const float* Wv    = (const float*)d_in[7];
    const float* bv    = (const float*)d_in[8];
    const float* Wp    = (const float*)d_in[9];
    const float* ub    = (const float*)d_in[10];
    const float* vb    = (const float*)d_in[11];
    const float* Wo    = (const float*)d_in[12];
    const float* bo    = (const float*)d_in[13];
    float* out = (float*)d_out;

    char* wsb = (char*)d_ws;
    short* ctxb = (short*)wsb;                                   // 4 MB bf16
    short* xnb  = (short*)(wsb + 4194304);                       // 4 MB bf16
    short* peb  = (short*)(wsb + 4194304 + 4194304);             // 1 MB bf16
    short* WT   = (short*)(wsb + 4194304 + 4194304 + 1048576);   // 640 KB bf16 (5 mats)
    short* q    = WT  + (size_t)5*65536;                         // 4 MB
    short* kbf  = q   + (size_t)NROW*DMODEL;                     // 4 MB
    short* vT   = kbf + (size_t)NROW*DMODEL;                     // 4 MB
    short* pbf  = vT  + (size_t)NROW*DMODEL;                     // 1 MB

    pe_kernel<<<1024, 256, 0, stream>>>(peb);
    ln_kernel<<<2048, 256, 0, stream>>>(x, gamma, beta, xnb);
    wcvt_kernel<<<dim3(4,4,5), 256, 0, stream>>>(Wq, Wk, Wv, Wp, Wo, WT);
    projmm_kernel<<<416, 256, 0, stream>>>(xnb, peb, WT, bq, bk, bv, q, kbf, vT, pbf);
    attn_mfma_kernel<<<4096, 64, 0, stream>>>(q, kbf, pbf, vT, ub, vb, ctxb);
    outmm_kernel<<<128, 256, 0, stream>>>(ctxb, WT + (size_t)4*65536, bo, out);
}

// Round 10
// 248.244 us; speedup vs baseline: 2.2452x; 1.0055x over previous
//
#include <hip/hip_runtime.h>
#include <hip/hip_bf16.h>
#include <math.h>

#define L_SEQ 2048
#define NB 4
#define DMODEL 256
#define NH 8
#define DHEAD 32
#define NROW (NB*L_SEQ)

typedef __attribute__((ext_vector_type(8))) short short8;
typedef __attribute__((ext_vector_type(4))) float f32x4;

__device__ __forceinline__ float bf2f(short v) {
    union { unsigned u; float f; } x; x.u = ((unsigned)(unsigned short)v) << 16; return x.f;
}
__device__ __forceinline__ short f2bf(float f) {
    union { float f; unsigned u; } x; x.f = f;
    unsigned r = x.u + 0x7fff + ((x.u >> 16) & 1);
    return (short)(r >> 16);
}
__device__ __forceinline__ short8 zero8() {
    short8 z;
    #pragma unroll
    for (int i = 0; i < 8; ++i) z[i] = 0;
    return z;
}

// ---------------- sinusoidal positional encoding (bf16) ----------------
__global__ void pe_kernel(short* __restrict__ peb) {
    int idx = blockIdx.x*256 + threadIdx.x;      // 2048*128 total
    int l = idx >> 7, m = idx & 127;
    double ang = (double)l * exp((double)m * (-9.210340371976184/128.0));
    unsigned s = (unsigned)(unsigned short)f2bf((float)sin(ang));
    unsigned c = (unsigned)(unsigned short)f2bf((float)cos(ang));
    *(unsigned*)(peb + l*DMODEL + 2*m) = s | (c << 16);
}

// ---------------- layernorm (one wave per row) -> bf16 ----------------
__global__ void ln_kernel(const float* __restrict__ x, const float* __restrict__ gamma,
                          const float* __restrict__ beta, short* __restrict__ xnb) {
    int lane = threadIdx.x & 63;
    int row  = blockIdx.x*4 + (threadIdx.x >> 6);
    const float4 a = *(const float4*)(x + (size_t)row*DMODEL + lane*4);
    float s  = a.x+a.y+a.z+a.w;
    float s2 = a.x*a.x+a.y*a.y+a.z*a.z+a.w*a.w;
    #pragma unroll
    for (int o = 32; o; o >>= 1) { s += __shfl_xor(s,o); s2 += __shfl_xor(s2,o); }
    float mu  = s * (1.f/DMODEL);
    float var = s2 * (1.f/DMODEL) - mu*mu;
    float rst = rsqrtf(var + 1e-3f);
    const float4 g  = *(const float4*)(gamma + lane*4);
    const float4 bt = *(const float4*)(beta  + lane*4);
    short4 o;
    o.x = f2bf((a.x-mu)*rst*g.x + bt.x);
    o.y = f2bf((a.y-mu)*rst*g.y + bt.y);
    o.z = f2bf((a.z-mu)*rst*g.z + bt.z);
    o.w = f2bf((a.w-mu)*rst*g.w + bt.w);
    *(short4*)(xnb + (size_t)row*DMODEL + lane*4) = o;
}

// ---------------- weight transpose+convert: W[k][n] f32 -> WT[n][k] bf16 (5 mats) ----------------
__global__ __launch_bounds__(256)
void wcvt_kernel(const float* __restrict__ W0, const float* __restrict__ W1,
                 const float* __restrict__ W2, const float* __restrict__ W3,
                 const float* __restrict__ W4, short* __restrict__ WT) {
    const float* W = (blockIdx.z==0)?W0:(blockIdx.z==1)?W1:(blockIdx.z==2)?W2:
                     (blockIdx.z==3)?W3:W4;
    short* O = WT + (size_t)blockIdx.z*65536;
    __shared__ float s[64][65];
    const int k0 = blockIdx.x*64, n0 = blockIdx.y*64;
    const int c = threadIdx.x & 63, r4 = threadIdx.x >> 6;
    #pragma unroll
    for (int i = 0; i < 16; ++i) {
        int r = r4 + 4*i;
        s[c][r] = W[(size_t)(k0+r)*256 + n0 + c];
    }
    __syncthreads();
    #pragma unroll
    for (int i = 0; i < 16; ++i) {
        int rn = r4 + 4*i;
        O[(size_t)(n0+rn)*256 + k0 + c] = f2bf(s[rn][c]);
    }
}

// ---------------- bf16 MFMA projections: C = A @ W (+bias) ----------------
// z==2 (V projection) writes DIRECTLY to vT[b,h,d,l].
__global__ __launch_bounds__(256, 2)
void projmm_kernel(const short* __restrict__ xnb, const short* __restrict__ peb,
                   const short* __restrict__ WT,
                   const float* __restrict__ bq, const float* __restrict__ bk,
                   const float* __restrict__ bv,
                   short* __restrict__ q, short* __restrict__ kb,
                   short* __restrict__ vT, short* __restrict__ pbuf) {
    const int bid = blockIdx.x;
    int z, rb;
    if (bid < 384) { z = bid >> 7; rb = bid & 127; }
    else           { z = 3;        rb = bid - 384; }
    const short* A = (z == 3) ? peb : xnb;
    const short* W = WT + (size_t)z*65536;
    const int t = threadIdx.x;
    const int w = t >> 6, l = t & 63, lc = l & 15, lg = l >> 4;
    const int m0 = rb*64 + 16*w;

    short8 afr[8];
    #pragma unroll
    for (int ks = 0; ks < 8; ++ks)
        afr[ks] = *(const short8*)(A + (size_t)(m0+lc)*256 + ks*32 + lg*8);

    const f32x4 zf = {0.f,0.f,0.f,0.f};
    f32x4 acc[16];
    #pragma unroll
    for (int ct = 0; ct < 16; ++ct) acc[ct] = zf;

    #pragma unroll
    for (int ct = 0; ct < 16; ++ct) {
        #pragma unroll
        for (int ks = 0; ks < 8; ++ks) {
            const short8 bfr = *(const short8*)(W + (size_t)(ct*16+lc)*256 + ks*32 + lg*8);
            acc[ct] = __builtin_amdgcn_mfma_f32_16x16x32_bf16(afr[ks], bfr, acc[ct], 0, 0, 0);
        }
    }

    if (z == 2) {
        const int bb = m0 >> 11;
        const int l0 = (m0 & 2047) + 4*lg;
        #pragma unroll
        for (int ct = 0; ct < 16; ++ct) {
            const int cc = ct*16 + lc;
            const float bias = bv[cc];
            const int hh = cc >> 5, dd = cc & 31;
            short4 o;
            o.x = f2bf(acc[ct][0] + bias);
            o.y = f2bf(acc[ct][1] + bias);
            o.z = f2bf(acc[ct][2] + bias);
            o.w = f2bf(acc[ct][3] + bias);
            *(short4*)(vT + ((size_t)((bb*NH + hh)*DHEAD + dd))*L_SEQ + l0) = o;
        }
    } else {
        #pragma unroll
        for (int ct = 0; ct < 16; ++ct) {
            const int cc = ct*16 + lc;
            float bias = 0.f;
            if (z == 0) bias = bq[cc];
            else if (z == 1) bias = bk[cc];
            #pragma unroll
            for (int r = 0; r < 4; ++r) {
                const size_t idx = (size_t)(m0 + 4*lg + r)*DMODEL + cc;
                const short v = f2bf(acc[ct][r] + bias);
                if (z == 0)      q[idx]    = v;
                else if (z == 1) kb[idx]   = v;
                else             pbuf[idx] = v;
            }
        }
    }
}

// ---------------- bf16 MFMA out-projection: out = ctxb @ Wo + bo (f32 out) ----------------
__global__ __launch_bounds__(256, 2)
void outmm_kernel(const short* __restrict__ ctxb, const short* __restrict__ WTo,
                  const float* __restrict__ bo, float* __restrict__ out) {
    const int rb = blockIdx.x;
    const int t = threadIdx.x;
    const int w = t >> 6, l = t & 63, lc = l & 15, lg = l >> 4;
    const int m0 = rb*64 + 16*w;

    short8 afr[8];
    #pragma unroll
    for (int ks = 0; ks < 8; ++ks)
        afr[ks] = *(const short8*)(ctxb + (size_t)(m0+lc)*256 + ks*32 + lg*8);

    const f32x4 zf = {0.f,0.f,0.f,0.f};
    f32x4 acc[16];
    #pragma unroll
    for (int ct = 0; ct < 16; ++ct) acc[ct] = zf;

    #pragma unroll
    for (int ct = 0; ct < 16; ++ct) {
        #pragma unroll
        for (int ks = 0; ks < 8; ++ks) {
            const short8 bfr = *(const short8*)(WTo + (size_t)(ct*16+lc)*256 + ks*32 + lg*8);
            acc[ct] = __builtin_amdgcn_mfma_f32_16x16x32_bf16(afr[ks], bfr, acc[ct], 0, 0, 0);
        }
    }

    #pragma unroll
    for (int ct = 0; ct < 16; ++ct) {
        const int cc = ct*16 + lc;
        const float bias = bo[cc];
        #pragma unroll
        for (int r = 0; r < 4; ++r)
            out[(size_t)(m0 + 4*lg + r)*DMODEL + cc] = acc[ct][r] + bias;
    }
}

// ---------------- fused MFMA attention: 4 independent waves/block, barrier-free ----------------
// Round 9 showed 1-wave workgroups only reach ~6.7 waves/CU resident (Occupancy 21%,
// VALUBusy cross-check agrees) -> pack 4 INDEPENDENT waves per 256-thread block (no
// barriers; wave-private LDS slices, rounds 5/6 pattern). 31 KB LDS -> 4 blocks/CU =
// 16 waves/CU, grid 1024 = one full round. No min-waves clause (it forces spills).
// Serial-chain trims: q-fragments pre-scaled by KSC (scores born in log2 domain);
// l_r kept lane-partial (no per-step sum shuffles; one epilogue reduce).
__global__ __launch_bounds__(256)
void attn_mfma_kernel(const short* __restrict__ qg, const short* __restrict__ kb,
                      const short* __restrict__ pb, const short* __restrict__ vT,
                      const float* __restrict__ ub, const float* __restrict__ vb,
                      short* __restrict__ ctxb) {
    // swizzled decode: all blocks of head h land on XCD h
    const int i0  = blockIdx.x;
    const int xcd = i0 & 7, idx = i0 >> 3;      // idx in [0,128)
    const int h   = xcd;
    const int b   = idx >> 5;
    const int w   = threadIdx.x >> 6;
    const int q0  = (idx & 31) * 64 + 16 * w;
    const int l   = threadIdx.x & 63;
    const int lc  = l & 15;
    const int lg  = l >> 4;

    __shared__ float    sT[4][17][84];   // per-wave: rows 0..15 = T[q0+lc], row 16 = boundary
    __shared__ unsigned sPk[4][16][32];  // per-wave P bf16-pairs, XOR-swizzled; reused as ctx

    const float KSC = 0.0625f * 1.44269504088896340736f;  // (1/16)*log2(e)

    // fragment setup: one q load per row + in-register bias adds, PRE-SCALED by KSC
    const size_t qrow = ((size_t)(b*L_SEQ + q0 + lc))*DMODEL + h*DHEAD + lg*8;
    const short8 qraw = *(const short8*)(qg + qrow);
    short8 qraw_sh = zero8();
    {
        const int r2 = q0 + lc + 1;
        if (r2 < L_SEQ)
            qraw_sh = *(const short8*)(qg + ((size_t)(b*L_SEQ + r2))*DMODEL + h*DHEAD + lg*8);
    }
    short8 aqu, aqv, aqv_sh;
    #pragma unroll
    for (int j = 0; j < 8; ++j) {
        const float u_ = ub[h*DHEAD + lg*8 + j];
        const float v_ = vb[h*DHEAD + lg*8 + j];
        const float f  = bf2f(qraw[j]);
        aqu[j]    = f2bf((f + u_) * KSC);
        aqv[j]    = f2bf((f + v_) * KSC);
        aqv_sh[j] = f2bf((bf2f(qraw_sh[j]) + v_) * KSC);
    }

    float m_r = -3.0e38f, l_r = 0.f;     // l_r is LANE-PARTIAL (reduced in epilogue)
    f32x4 acc0 = {0.f,0.f,0.f,0.f}, acc1 = {0.f,0.f,0.f,0.f};

    const short* kbase = kb + ((size_t)(b*L_SEQ))*DMODEL + h*DHEAD;
    const short* pbase = pb + h*DHEAD;
    const short* vbase = vT + ((size_t)((b*NH + h)*DHEAD))*L_SEQ;
    const f32x4 zf = {0.f, 0.f, 0.f, 0.f};

    // ptilde loader for window slot cc at tile k0n: A-row jj = 16*cc + lc
    auto loadP = [&](int k0n, int cc) -> short8 {
        const int rho = (k0n - q0 - 17) + 16*cc + lc;
        if (rho == -1) return zero8();
        const int pr = rho + (rho < 0 ? (L_SEQ+1) : 0);
        return *(const short8*)(pbase + (size_t)pr*DMODEL + lg*8);
    };

    // persistent A-fragments
    short8 kfrag[4], pfrag[5];
    #pragma unroll
    for (int ct = 0; ct < 4; ++ct)
        kfrag[ct] = *(const short8*)(kbase + (size_t)(ct*16 + lc)*DMODEL + lg*8);
    #pragma unroll
    for (int cc = 0; cc < 5; ++cc) pfrag[cc] = loadP(0, cc);

    const int colc = 4*lg + 15 - lc;     // gather col = 16*ct + colc + r
    const int swkey = lc & 7;

    for (int k0 = 0; k0 < L_SEQ; k0 += 64) {
        const int diff = k0 - q0;

        // ---- content: S^T tiles (A = K, B = Qu) ----
        f32x4 cts[4];
        #pragma unroll
        for (int ct = 0; ct < 4; ++ct)
            cts[ct] = __builtin_amdgcn_mfma_f32_16x16x32_bf16(kfrag[ct], aqu, zf, 0, 0, 0);

        // ---- pos band: unshifted (rows lc) + shifted (boundary row 16, lc==15 lanes) ----
        #pragma unroll
        for (int cc = 0; cc < 5; ++cc) {
            f32x4 tt = __builtin_amdgcn_mfma_f32_16x16x32_bf16(pfrag[cc], aqv, zf, 0, 0, 0);
            *(f32x4*)&sT[w][lc][16*cc + 4*lg] = tt;
            f32x4 tt2 = __builtin_amdgcn_mfma_f32_16x16x32_bf16(pfrag[cc], aqv_sh, zf, 0, 0, 0);
            if (lc == 15) *(f32x4*)&sT[w][16][16*cc + 4*lg] = tt2;
        }

        // ---- rotate p-window (slide 64 = 4 slots) + prefetch next tile ----
        pfrag[0] = pfrag[4];
        if (k0 + 64 < L_SEQ) {
            #pragma unroll
            for (int ct = 0; ct < 4; ++ct)
                kfrag[ct] = *(const short8*)(kbase + (size_t)(k0 + 64 + ct*16 + lc)*DMODEL + lg*8);
            #pragma unroll
            for (int cc = 1; cc < 5; ++cc) pfrag[cc] = loadP(k0 + 64, cc);
        }
        // V fragments for the CURRENT tile (consumed after softmax)
        short8 vfrag[2][2];
        #pragma unroll
        for (int dt = 0; dt < 2; ++dt)
            #pragma unroll
            for (int kc = 0; kc < 2; ++kc)
                vfrag[dt][kc] = *(const short8*)(vbase + (size_t)(16*dt + lc)*L_SEQ + k0 + kc*32 + lg*8);

        asm volatile("s_waitcnt lgkmcnt(0)" ::: "memory");  // sT writes visible (intra-wave)

        // ---- rel-shift gather + combine (log2 domain already) ----
        float sc[4][4];
        const int cthr = 17 - diff;   // up = (col >= cthr), col in [0,78]
        if (cthr > 78) {
            const float* rowp = &sT[w][lc][0];
            #pragma unroll
            for (int ct = 0; ct < 4; ++ct)
                #pragma unroll
                for (int r = 0; r < 4; ++r)
                    sc[ct][r] = cts[ct][r] + rowp[16*ct + colc + r];
        } else if (cthr <= 0) {
            const float* rowp = &sT[w][lc+1][0];
            #pragma unroll
            for (int ct = 0; ct < 4; ++ct)
                #pragma unroll
                for (int r = 0; r < 4; ++r)
                    sc[ct][r] = cts[ct][r] + rowp[16*ct + colc + r];
        } else {
            #pragma unroll
            for (int ct = 0; ct < 4; ++ct)
                #pragma unroll
                for (int r = 0; r < 4; ++r) {
                    const int col = 16*ct + colc + r;
                    const int up = (col >= cthr) ? 1 : 0;
                    sc[ct][r] = cts[ct][r] + sT[w][lc + up][col];
                }
        }

        // ---- softmax: lane owns row q0+lc; max-reduce only (l_r stays partial) ----
        float mx = sc[0][0];
        #pragma unroll
        for (int ct = 0; ct < 4; ++ct)
            #pragma unroll
            for (int r = 0; r < 4; ++r) mx = fmaxf(mx, sc[ct][r]);
        mx = fmaxf(mx, __shfl_xor(mx, 16));
        mx = fmaxf(mx, __shfl_xor(mx, 32));
        const float mn = fmaxf(m_r, mx);
        float ts = 0.f;
        #pragma unroll
        for (int ct = 0; ct < 4; ++ct)
            #pragma unroll
            for (int r = 0; r < 4; ++r) {
                sc[ct][r] = exp2f(sc[ct][r] - mn);
                ts += sc[ct][r];
            }
        const float alpha = exp2f(m_r - mn);
        m_r = mn;
        l_r = l_r*alpha + ts;

        // ---- pack P -> sPk (bf16 pairs, XOR-block swizzle) ----
        #pragma unroll
        for (int ct = 0; ct < 4; ++ct) {
            unsigned lo, hi;
            asm("v_cvt_pk_bf16_f32 %0, %1, %2" : "=v"(lo) : "v"(sc[ct][0]), "v"(sc[ct][1]));
            asm("v_cvt_pk_bf16_f32 %0, %1, %2" : "=v"(hi) : "v"(sc[ct][2]), "v"(sc[ct][3]));
            const int kbi = 2*ct + (lg >> 1);
            const int idx2 = ((kbi ^ swkey) << 2) + 2*(lg & 1);
            *(uint2*)&sPk[w][lc][idx2] = make_uint2(lo, hi);
        }
        #pragma unroll
        for (int r = 0; r < 4; ++r) { acc0[r] *= alpha; acc1[r] *= alpha; }

        asm volatile("s_waitcnt lgkmcnt(0)" ::: "memory");  // sPk writes visible (intra-wave)

        // ---- PV: ctx^T += V^T . P ----
        #pragma unroll
        for (int kc = 0; kc < 2; ++kc) {
            const int idx2 = ((4*kc + lg) ^ swkey) << 2;
            const short8 bp = *(const short8*)&sPk[w][lc][idx2];
            acc0 = __builtin_amdgcn_mfma_f32_16x16x32_bf16(vfrag[0][kc], bp, acc0, 0, 0, 0);
            acc1 = __builtin_amdgcn_mfma_f32_16x16x32_bf16(vfrag[1][kc], bp, acc1, 0, 0, 0);
        }
    }

    // ---- epilogue: reduce lane-partial l_r, transpose ctx^T via sPk, emit bf16 ----
    l_r += __shfl_xor(l_r, 16);
    l_r += __shfl_xor(l_r, 32);
    asm volatile("s_waitcnt lgkmcnt(0)" ::: "memory");
    float* sCt = (float*)&sPk[w][0][0];   // [16][32] f32 view
    const float inv = 1.f / l_r;
    {
        f32x4 o0, o1;
        #pragma unroll
        for (int r = 0; r < 4; ++r) { o0[r] = acc0[r]*inv; o1[r] = acc1[r]*inv; }
        *(f32x4*)&sCt[lc*32 + 4*lg]      = o0;
        *(f32x4*)&sCt[lc*32 + 16 + 4*lg] = o1;
    }
    asm volatile("s_waitcnt lgkmcnt(0)" ::: "memory");
    const int rr = l >> 2;
    const int c0 = (l & 3) * 8;
    short8 ob;
    #pragma unroll
    for (int j = 0; j < 8; ++j) ob[j] = f2bf(sCt[rr*32 + c0 + j]);
    *(short8*)(ctxb + ((size_t)(b*L_SEQ + q0 + rr))*DMODEL + h*DHEAD + c0) = ob;
}

extern "C" void kernel_launch(void* const* d_in, const int* in_sizes, int n_in,
                              void* d_out, int out_size, void* d_ws, size_t ws_size,
                              hipStream_t stream) {
    (void)in_sizes; (void)n_in; (void)out_size; (void)ws_size;
    const float* x     = (const float*)d_in[0];
    const float* gamma = (const float*)d_in[1];
    const float* beta  = (const float*)d_in[2];
    const float* Wq    = (const float*)d_in[3];
    const float* bq    = (const float*)d_in[4];
    const float* Wk    = (const float*)d_in[5];
    const float* bk    = (const float*)d_in[6];
    const float* Wv    = (const float*)d_in[7];
    const float* bv    = (const float*)d_in[8];
    const float* Wp    = (const float*)d_in[9];
    const float* ub    = (const float*)d_in[10];
    const float* vb    = (const float*)d_in[11];
    const float* Wo    = (const float*)d_in[12];
    const float* bo    = (const float*)d_in[13];
    float* out = (float*)d_out;

    char* wsb = (char*)d_ws;
    short* ctxb = (short*)wsb;                                   // 4 MB bf16
    short* xnb  = (short*)(wsb + 4194304);                       // 4 MB bf16
    short* peb  = (short*)(wsb + 4194304 + 4194304);             // 1 MB bf16
    short* WT   = (short*)(wsb + 4194304 + 4194304 + 1048576);   // 640 KB bf16 (5 mats)
    short* q    = WT  + (size_t)5*65536;                         // 4 MB
    short* kbf  = q   + (size_t)NROW*DMODEL;                     // 4 MB
    short* vT   = kbf + (size_t)NROW*DMODEL;                     // 4 MB
    short* pbf  = vT  + (size_t)NROW*DMODEL;                     // 1 MB

    pe_kernel<<<1024, 256, 0, stream>>>(peb);
    ln_kernel<<<2048, 256, 0, stream>>>(x, gamma, beta, xnb);
    wcvt_kernel<<<dim3(4,4,5), 256, 0, stream>>>(Wq, Wk, Wv, Wp, Wo, WT);
    projmm_kernel<<<416, 256, 0, stream>>>(xnb, peb, WT, bq, bk, bv, q, kbf, vT, pbf);
    attn_mfma_kernel<<<1024, 256, 0, stream>>>(q, kbf, pbf, vT, ub, vb, ctxb);
    outmm_kernel<<<128, 256, 0, stream>>>(ctxb, WT + (size_t)4*65536, bo, out);
}

// Round 11
// 242.661 us; speedup vs baseline: 2.2968x; 1.0230x over previous
//
#include <hip/hip_runtime.h>
#include <hip/hip_bf16.h>
#include <math.h>

#define L_SEQ 2048
#define NB 4
#define DMODEL 256
#define NH 8
#define DHEAD 32
#define NROW (NB*L_SEQ)

typedef __attribute__((ext_vector_type(8))) short short8;
typedef __attribute__((ext_vector_type(4))) float f32x4;

__device__ __forceinline__ float bf2f(short v) {
    union { unsigned u; float f; } x; x.u = ((unsigned)(unsigned short)v) << 16; return x.f;
}
__device__ __forceinline__ short f2bf(float f) {
    union { float f; unsigned u; } x; x.f = f;
    unsigned r = x.u + 0x7fff + ((x.u >> 16) & 1);
    return (short)(r >> 16);
}
__device__ __forceinline__ short8 zero8() {
    short8 z;
    #pragma unroll
    for (int i = 0; i < 8; ++i) z[i] = 0;
    return z;
}

// ---------------- fused prep: layernorm (blocks 0..2047) + PE (2048..3071) + wcvt (3072..3151) ----------------
__global__ __launch_bounds__(256)
void prep_kernel(const float* __restrict__ x, const float* __restrict__ gamma,
                 const float* __restrict__ beta, short* __restrict__ xnb,
                 short* __restrict__ peb,
                 const float* __restrict__ W0, const float* __restrict__ W1,
                 const float* __restrict__ W2, const float* __restrict__ W3,
                 const float* __restrict__ W4, short* __restrict__ WT) {
    const int bid = blockIdx.x;
    __shared__ float s[64][65];
    if (bid < 2048) {
        // ---- layernorm, 4 rows/block ----
        int lane = threadIdx.x & 63;
        int row  = bid*4 + (threadIdx.x >> 6);
        const float4 a = *(const float4*)(x + (size_t)row*DMODEL + lane*4);
        float sm  = a.x+a.y+a.z+a.w;
        float s2 = a.x*a.x+a.y*a.y+a.z*a.z+a.w*a.w;
        #pragma unroll
        for (int o = 32; o; o >>= 1) { sm += __shfl_xor(sm,o); s2 += __shfl_xor(s2,o); }
        float mu  = sm * (1.f/DMODEL);
        float var = s2 * (1.f/DMODEL) - mu*mu;
        float rst = rsqrtf(var + 1e-3f);
        const float4 g  = *(const float4*)(gamma + lane*4);
        const float4 bt = *(const float4*)(beta  + lane*4);
        short4 o;
        o.x = f2bf((a.x-mu)*rst*g.x + bt.x);
        o.y = f2bf((a.y-mu)*rst*g.y + bt.y);
        o.z = f2bf((a.z-mu)*rst*g.z + bt.z);
        o.w = f2bf((a.w-mu)*rst*g.w + bt.w);
        *(short4*)(xnb + (size_t)row*DMODEL + lane*4) = o;
    } else if (bid < 3072) {
        // ---- sinusoidal PE ----
        int idx = (bid-2048)*256 + threadIdx.x;
        int l = idx >> 7, m = idx & 127;
        double ang = (double)l * exp((double)m * (-9.210340371976184/128.0));
        unsigned sv = (unsigned)(unsigned short)f2bf((float)sin(ang));
        unsigned cv = (unsigned)(unsigned short)f2bf((float)cos(ang));
        *(unsigned*)(peb + l*DMODEL + 2*m) = sv | (cv << 16);
    } else {
        // ---- weight transpose+convert ----
        const int r  = bid - 3072;           // 0..79
        const int z  = r >> 4, rr = r & 15;
        const float* W = (z==0)?W0:(z==1)?W1:(z==2)?W2:(z==3)?W3:W4;
        short* O = WT + (size_t)z*65536;
        const int k0 = (rr >> 2)*64, n0 = (rr & 3)*64;
        const int c = threadIdx.x & 63, r4 = threadIdx.x >> 6;
        #pragma unroll
        for (int i = 0; i < 16; ++i) {
            int rw = r4 + 4*i;
            s[c][rw] = W[(size_t)(k0+rw)*256 + n0 + c];
        }
        __syncthreads();
        #pragma unroll
        for (int i = 0; i < 16; ++i) {
            int rn = r4 + 4*i;
            O[(size_t)(n0+rn)*256 + k0 + c] = f2bf(s[rn][c]);
        }
    }
}

// ---------------- bf16 MFMA projections: C = A @ W (+bias) ----------------
// z==2 (V projection) writes DIRECTLY to vT[b,h,d,l].
__global__ __launch_bounds__(256, 2)
void projmm_kernel(const short* __restrict__ xnb, const short* __restrict__ peb,
                   const short* __restrict__ WT,
                   const float* __restrict__ bq, const float* __restrict__ bk,
                   const float* __restrict__ bv,
                   short* __restrict__ q, short* __restrict__ kb,
                   short* __restrict__ vT, short* __restrict__ pbuf) {
    const int bid = blockIdx.x;
    int z, rb;
    if (bid < 384) { z = bid >> 7; rb = bid & 127; }
    else           { z = 3;        rb = bid - 384; }
    const short* A = (z == 3) ? peb : xnb;
    const short* W = WT + (size_t)z*65536;
    const int t = threadIdx.x;
    const int w = t >> 6, l = t & 63, lc = l & 15, lg = l >> 4;
    const int m0 = rb*64 + 16*w;

    short8 afr[8];
    #pragma unroll
    for (int ks = 0; ks < 8; ++ks)
        afr[ks] = *(const short8*)(A + (size_t)(m0+lc)*256 + ks*32 + lg*8);

    const f32x4 zf = {0.f,0.f,0.f,0.f};
    f32x4 acc[16];
    #pragma unroll
    for (int ct = 0; ct < 16; ++ct) acc[ct] = zf;

    #pragma unroll
    for (int ct = 0; ct < 16; ++ct) {
        #pragma unroll
        for (int ks = 0; ks < 8; ++ks) {
            const short8 bfr = *(const short8*)(W + (size_t)(ct*16+lc)*256 + ks*32 + lg*8);
            acc[ct] = __builtin_amdgcn_mfma_f32_16x16x32_bf16(afr[ks], bfr, acc[ct], 0, 0, 0);
        }
    }

    if (z == 2) {
        const int bb = m0 >> 11;
        const int l0 = (m0 & 2047) + 4*lg;
        #pragma unroll
        for (int ct = 0; ct < 16; ++ct) {
            const int cc = ct*16 + lc;
            const float bias = bv[cc];
            const int hh = cc >> 5, dd = cc & 31;
            short4 o;
            o.x = f2bf(acc[ct][0] + bias);
            o.y = f2bf(acc[ct][1] + bias);
            o.z = f2bf(acc[ct][2] + bias);
            o.w = f2bf(acc[ct][3] + bias);
            *(short4*)(vT + ((size_t)((bb*NH + hh)*DHEAD + dd))*L_SEQ + l0) = o;
        }
    } else {
        #pragma unroll
        for (int ct = 0; ct < 16; ++ct) {
            const int cc = ct*16 + lc;
            float bias = 0.f;
            if (z == 0) bias = bq[cc];
            else if (z == 1) bias = bk[cc];
            #pragma unroll
            for (int r = 0; r < 4; ++r) {
                const size_t idx = (size_t)(m0 + 4*lg + r)*DMODEL + cc;
                const short v = f2bf(acc[ct][r] + bias);
                if (z == 0)      q[idx]    = v;
                else if (z == 1) kb[idx]   = v;
                else             pbuf[idx] = v;
            }
        }
    }
}

// ---------------- bf16 MFMA out-projection: out = ctxb @ Wo + bo (f32 out) ----------------
__global__ __launch_bounds__(256, 2)
void outmm_kernel(const short* __restrict__ ctxb, const short* __restrict__ WTo,
                  const float* __restrict__ bo, float* __restrict__ out) {
    const int rb = blockIdx.x;
    const int t = threadIdx.x;
    const int w = t >> 6, l = t & 63, lc = l & 15, lg = l >> 4;
    const int m0 = rb*64 + 16*w;

    short8 afr[8];
    #pragma unroll
    for (int ks = 0; ks < 8; ++ks)
        afr[ks] = *(const short8*)(ctxb + (size_t)(m0+lc)*256 + ks*32 + lg*8);

    const f32x4 zf = {0.f,0.f,0.f,0.f};
    f32x4 acc[16];
    #pragma unroll
    for (int ct = 0; ct < 16; ++ct) acc[ct] = zf;

    #pragma unroll
    for (int ct = 0; ct < 16; ++ct) {
        #pragma unroll
        for (int ks = 0; ks < 8; ++ks) {
            const short8 bfr = *(const short8*)(WTo + (size_t)(ct*16+lc)*256 + ks*32 + lg*8);
            acc[ct] = __builtin_amdgcn_mfma_f32_16x16x32_bf16(afr[ks], bfr, acc[ct], 0, 0, 0);
        }
    }

    #pragma unroll
    for (int ct = 0; ct < 16; ++ct) {
        const int cc = ct*16 + lc;
        const float bias = bo[cc];
        #pragma unroll
        for (int r = 0; r < 4; ++r)
            out[(size_t)(m0 + 4*lg + r)*DMODEL + cc] = acc[ct][r] + bias;
    }
}

// ---------------- fused MFMA attention: 4 independent waves/block, barrier-free ----------------
// Round 10 null result (1-wave vs 4-wave blocks identical) -> limiter is the per-tile
// SERIAL CHAIN, not occupancy. This round: defer-max (T13). m_r stays frozen while
// per-lane max grows < 2^8; the wave-wide max-reduce (2 serial shuffles) + acc rescale
// run only in the rare rescale branch (wave-uniform). exp2 issues right after gather.
// P <= 256 in bf16 (same relative error); l_r/acc scaling invariant preserved.
__global__ __launch_bounds__(256)
void attn_mfma_kernel(const short* __restrict__ qg, const short* __restrict__ kb,
                      const short* __restrict__ pb, const short* __restrict__ vT,
                      const float* __restrict__ ub, const float* __restrict__ vb,
                      short* __restrict__ ctxb) {
    // swizzled decode: all blocks of head h land on XCD h
    const int i0  = blockIdx.x;
    const int xcd = i0 & 7, idx = i0 >> 3;      // idx in [0,128)
    const int h   = xcd;
    const int b   = idx >> 5;
    const int w   = threadIdx.x >> 6;
    const int q0  = (idx & 31) * 64 + 16 * w;
    const int l   = threadIdx.x & 63;
    const int lc  = l & 15;
    const int lg  = l >> 4;

    __shared__ float    sT[4][17][84];   // per-wave: rows 0..15 = T[q0+lc], row 16 = boundary
    __shared__ unsigned sPk[4][16][32];  // per-wave P bf16-pairs, XOR-swizzled; reused as ctx

    const float KSC = 0.0625f * 1.44269504088896340736f;  // (1/16)*log2(e)

    // fragment setup: one q load per row + in-register bias adds, PRE-SCALED by KSC
    const size_t qrow = ((size_t)(b*L_SEQ + q0 + lc))*DMODEL + h*DHEAD + lg*8;
    const short8 qraw = *(const short8*)(qg + qrow);
    short8 qraw_sh = zero8();
    {
        const int r2 = q0 + lc + 1;
        if (r2 < L_SEQ)
            qraw_sh = *(const short8*)(qg + ((size_t)(b*L_SEQ + r2))*DMODEL + h*DHEAD + lg*8);
    }
    short8 aqu, aqv, aqv_sh;
    #pragma unroll
    for (int j = 0; j < 8; ++j) {
        const float u_ = ub[h*DHEAD + lg*8 + j];
        const float v_ = vb[h*DHEAD + lg*8 + j];
        const float f  = bf2f(qraw[j]);
        aqu[j]    = f2bf((f + u_) * KSC);
        aqv[j]    = f2bf((f + v_) * KSC);
        aqv_sh[j] = f2bf((bf2f(qraw_sh[j]) + v_) * KSC);
    }

    float m_r = -3.0e38f, l_r = 0.f;     // l_r is LANE-PARTIAL (reduced in epilogue)
    f32x4 acc0 = {0.f,0.f,0.f,0.f}, acc1 = {0.f,0.f,0.f,0.f};

    const short* kbase = kb + ((size_t)(b*L_SEQ))*DMODEL + h*DHEAD;
    const short* pbase = pb + h*DHEAD;
    const short* vbase = vT + ((size_t)((b*NH + h)*DHEAD))*L_SEQ;
    const f32x4 zf = {0.f, 0.f, 0.f, 0.f};

    // ptilde loader for window slot cc at tile k0n: A-row jj = 16*cc + lc
    auto loadP = [&](int k0n, int cc) -> short8 {
        const int rho = (k0n - q0 - 17) + 16*cc + lc;
        if (rho == -1) return zero8();
        const int pr = rho + (rho < 0 ? (L_SEQ+1) : 0);
        return *(const short8*)(pbase + (size_t)pr*DMODEL + lg*8);
    };

    // persistent A-fragments
    short8 kfrag[4], pfrag[5];
    #pragma unroll
    for (int ct = 0; ct < 4; ++ct)
        kfrag[ct] = *(const short8*)(kbase + (size_t)(ct*16 + lc)*DMODEL + lg*8);
    #pragma unroll
    for (int cc = 0; cc < 5; ++cc) pfrag[cc] = loadP(0, cc);

    const int colc = 4*lg + 15 - lc;     // gather col = 16*ct + colc + r
    const int swkey = lc & 7;

    for (int k0 = 0; k0 < L_SEQ; k0 += 64) {
        const int diff = k0 - q0;

        // ---- content: S^T tiles (A = K, B = Qu) ----
        f32x4 cts[4];
        #pragma unroll
        for (int ct = 0; ct < 4; ++ct)
            cts[ct] = __builtin_amdgcn_mfma_f32_16x16x32_bf16(kfrag[ct], aqu, zf, 0, 0, 0);

        // ---- pos band: unshifted (rows lc) + shifted (boundary row 16, lc==15 lanes) ----
        #pragma unroll
        for (int cc = 0; cc < 5; ++cc) {
            f32x4 tt = __builtin_amdgcn_mfma_f32_16x16x32_bf16(pfrag[cc], aqv, zf, 0, 0, 0);
            *(f32x4*)&sT[w][lc][16*cc + 4*lg] = tt;
            f32x4 tt2 = __builtin_amdgcn_mfma_f32_16x16x32_bf16(pfrag[cc], aqv_sh, zf, 0, 0, 0);
            if (lc == 15) *(f32x4*)&sT[w][16][16*cc + 4*lg] = tt2;
        }

        // ---- rotate p-window (slide 64 = 4 slots) + prefetch next tile ----
        pfrag[0] = pfrag[4];
        if (k0 + 64 < L_SEQ) {
            #pragma unroll
            for (int ct = 0; ct < 4; ++ct)
                kfrag[ct] = *(const short8*)(kbase + (size_t)(k0 + 64 + ct*16 + lc)*DMODEL + lg*8);
            #pragma unroll
            for (int cc = 1; cc < 5; ++cc) pfrag[cc] = loadP(k0 + 64, cc);
        }
        // V fragments for the CURRENT tile (consumed after softmax)
        short8 vfrag[2][2];
        #pragma unroll
        for (int dt = 0; dt < 2; ++dt)
            #pragma unroll
            for (int kc = 0; kc < 2; ++kc)
                vfrag[dt][kc] = *(const short8*)(vbase + (size_t)(16*dt + lc)*L_SEQ + k0 + kc*32 + lg*8);

        asm volatile("s_waitcnt lgkmcnt(0)" ::: "memory");  // sT writes visible (intra-wave)

        // ---- rel-shift gather + combine (log2 domain already) ----
        float sc[4][4];
        const int cthr = 17 - diff;   // up = (col >= cthr), col in [0,78]
        if (cthr > 78) {
            const float* rowp = &sT[w][lc][0];
            #pragma unroll
            for (int ct = 0; ct < 4; ++ct)
                #pragma unroll
                for (int r = 0; r < 4; ++r)
                    sc[ct][r] = cts[ct][r] + rowp[16*ct + colc + r];
        } else if (cthr <= 0) {
            const float* rowp = &sT[w][lc+1][0];
            #pragma unroll
            for (int ct = 0; ct < 4; ++ct)
                #pragma unroll
                for (int r = 0; r < 4; ++r)
                    sc[ct][r] = cts[ct][r] + rowp[16*ct + colc + r];
        } else {
            #pragma unroll
            for (int ct = 0; ct < 4; ++ct)
                #pragma unroll
                for (int r = 0; r < 4; ++r) {
                    const int col = 16*ct + colc + r;
                    const int up = (col >= cthr) ? 1 : 0;
                    sc[ct][r] = cts[ct][r] + sT[w][lc + up][col];
                }
        }

        // ---- defer-max softmax (T13): rescale only when lane-max grew past THR ----
        float pmax = sc[0][0];
        #pragma unroll
        for (int ct = 0; ct < 4; ++ct)
            #pragma unroll
            for (int r = 0; r < 4; ++r) pmax = fmaxf(pmax, sc[ct][r]);
        if (!__all(pmax - m_r <= 8.0f)) {          // rare, wave-uniform branch
            float mx = fmaxf(pmax, __shfl_xor(pmax, 16));
            mx = fmaxf(mx, __shfl_xor(mx, 32));
            const float mn = fmaxf(m_r, mx);
            const float alpha = exp2f(m_r - mn);
            m_r = mn;
            l_r *= alpha;
            #pragma unroll
            for (int r = 0; r < 4; ++r) { acc0[r] *= alpha; acc1[r] *= alpha; }
        }
        float ts = 0.f;
        #pragma unroll
        for (int ct = 0; ct < 4; ++ct)
            #pragma unroll
            for (int r = 0; r < 4; ++r) {
                sc[ct][r] = exp2f(sc[ct][r] - m_r);   // <= 2^8
                ts += sc[ct][r];
            }
        l_r += ts;

        // ---- pack P -> sPk (bf16 pairs, XOR-block swizzle) ----
        #pragma unroll
        for (int ct = 0; ct < 4; ++ct) {
            unsigned lo, hi;
            asm("v_cvt_pk_bf16_f32 %0, %1, %2" : "=v"(lo) : "v"(sc[ct][0]), "v"(sc[ct][1]));
            asm("v_cvt_pk_bf16_f32 %0, %1, %2" : "=v"(hi) : "v"(sc[ct][2]), "v"(sc[ct][3]));
            const int kbi = 2*ct + (lg >> 1);
            const int idx2 = ((kbi ^ swkey) << 2) + 2*(lg & 1);
            *(uint2*)&sPk[w][lc][idx2] = make_uint2(lo, hi);
        }

        asm volatile("s_waitcnt lgkmcnt(0)" ::: "memory");  // sPk writes visible (intra-wave)

        // ---- PV: ctx^T += V^T . P ----
        #pragma unroll
        for (int kc = 0; kc < 2; ++kc) {
            const int idx2 = ((4*kc + lg) ^ swkey) << 2;
            const short8 bp = *(const short8*)&sPk[w][lc][idx2];
            acc0 = __builtin_amdgcn_mfma_f32_16x16x32_bf16(vfrag[0][kc], bp, acc0, 0, 0, 0);
            acc1 = __builtin_amdgcn_mfma_f32_16x16x32_bf16(vfrag[1][kc], bp, acc1, 0, 0, 0);
        }
    }

    // ---- epilogue: reduce lane-partial l_r, transpose ctx^T via sPk, emit bf16 ----
    l_r += __shfl_xor(l_r, 16);
    l_r += __shfl_xor(l_r, 32);
    asm volatile("s_waitcnt lgkmcnt(0)" ::: "memory");
    float* sCt = (float*)&sPk[w][0][0];   // [16][32] f32 view
    const float inv = 1.f / l_r;
    {
        f32x4 o0, o1;
        #pragma unroll
        for (int r = 0; r < 4; ++r) { o0[r] = acc0[r]*inv; o1[r] = acc1[r]*inv; }
        *(f32x4*)&sCt[lc*32 + 4*lg]      = o0;
        *(f32x4*)&sCt[lc*32 + 16 + 4*lg] = o1;
    }
    asm volatile("s_waitcnt lgkmcnt(0)" ::: "memory");
    const int rr = l >> 2;
    const int c0 = (l & 3) * 8;
    short8 ob;
    #pragma unroll
    for (int j = 0; j < 8; ++j) ob[j] = f2bf(sCt[rr*32 + c0 + j]);
    *(short8*)(ctxb + ((size_t)(b*L_SEQ + q0 + rr))*DMODEL + h*DHEAD + c0) = ob;
}

extern "C" void kernel_launch(void* const* d_in, const int* in_sizes, int n_in,
                              void* d_out, int out_size, void* d_ws, size_t ws_size,
                              hipStream_t stream) {
    (void)in_sizes; (void)n_in; (void)out_size; (void)ws_size;
    const float* x     = (const float*)d_in[0];
    const float* gamma = (const float*)d_in[1];
    const float* beta  = (const float*)d_in[2];
    const float* Wq    = (const float*)d_in[3];
    const float* bq    = (const float*)d_in[4];
    const float* Wk    = (const float*)d_in[5];
    const float* bk    = (const float*)d_in[6];
    const float* Wv    = (const float*)d_in[7];
    const float* bv    = (const float*)d_in[8];
    const float* Wp    = (const float*)d_in[9];
    const float* ub    = (const float*)d_in[10];
    const float* vb    = (const float*)d_in[11];
    const float* Wo    = (const float*)d_in[12];
    const float* bo    = (const float*)d_in[13];
    float* out = (float*)d_out;

    char* wsb = (char*)d_ws;
    short* ctxb = (short*)wsb;                                   // 4 MB bf16
    short* xnb  = (short*)(wsb + 4194304);                       // 4 MB bf16
    short* peb  = (short*)(wsb + 4194304 + 4194304);             // 1 MB bf16
    short* WT   = (short*)(wsb + 4194304 + 4194304 + 1048576);   // 640 KB bf16 (5 mats)
    short* q    = WT  + (size_t)5*65536;                         // 4 MB
    short* kbf  = q   + (size_t)NROW*DMODEL;                     // 4 MB
    short* vT   = kbf + (size_t)NROW*DMODEL;                     // 4 MB
    short* pbf  = vT  + (size_t)NROW*DMODEL;                     // 1 MB

    prep_kernel<<<3152, 256, 0, stream>>>(x, gamma, beta, xnb, peb,
                                          Wq, Wk, Wv, Wp, Wo, WT);
    projmm_kernel<<<416, 256, 0, stream>>>(xnb, peb, WT, bq, bk, bv, q, kbf, vT, pbf);
    attn_mfma_kernel<<<1024, 256, 0, stream>>>(q, kbf, pbf, vT, ub, vb, ctxb);
    outmm_kernel<<<128, 256, 0, stream>>>(ctxb, WT + (size_t)4*65536, bo, out);
}